// Round 8
// baseline (803.542 us; speedup 1.0000x reference)
//
#include <hip/hip_runtime.h>

#define NN 50000
#define NE 800000
#define INF 7
#define GD 16
#define LAT 64
#define HID 128

typedef unsigned short u16;
typedef __attribute__((ext_vector_type(8))) __bf16 bf16x8;
typedef __attribute__((ext_vector_type(4))) float f32x4;

__device__ __forceinline__ float bf2f(u16 u) {
  union { unsigned int i; float f; } v; v.i = ((unsigned int)u) << 16; return v.f;
}
__device__ __forceinline__ float blo(unsigned int u) {
  union { unsigned int i; float f; } v; v.i = u << 16; return v.f;
}
__device__ __forceinline__ float bhi(unsigned int u) {
  union { unsigned int i; float f; } v; v.i = u & 0xffff0000u; return v.f;
}
__device__ __forceinline__ u16 f2bf(float f) {
  union { float f; unsigned int i; } v; v.f = f;
  unsigned int x = v.i;
  return (u16)((x + 0x7fffu + ((x >> 16) & 1u)) >> 16);
}
// jax.nn.gelu approximate (tanh form) as x*sigmoid(2z) with v_rcp (r11-verified).
__device__ __forceinline__ float gelu(float x) {
  float u = x * x;
  float p = fmaf(0.044715f * u, x, x);
  float e = __expf(-1.5957691216057308f * p);
  return x * __builtin_amdgcn_rcpf(e + 1.0f);
}

// ---- consolidated weight pre-pack: 13 jobs in one dispatch.
struct PackJobs {
  const float* src[13];
  u16* dst[13];
  int K[13];
  int N[13];
  int KC[13];
};

__global__ void pack_all(PackJobs J) {
  const int j = blockIdx.y;
  const int KC = J.KC[j];
  const float* W = J.src[j];
  u16* out = J.dst[j];
  int t = blockIdx.x * blockDim.x + threadIdx.x;
  if (KC == 0) {            // gpad job
    if (t < 32) out[t] = (t < GD) ? f2bf(W[t]) : (u16)0;
    return;
  }
  const int K = J.K[j], N = J.N[j];
  const int NT = N >> 4;
  if (t >= KC * NT * 64) return;
  int l = t & 63;
  int nt = (t >> 6) % NT;
  int kc = t / (64 * NT);
  int n = nt * 16 + (l & 15);
  int kbase = kc * 32 + (l >> 4) * 8;
  ushort4 lo, hi;
  u16 v[8];
#pragma unroll
  for (int jj = 0; jj < 8; ++jj) {
    int k = kbase + jj;
    v[jj] = (k < K) ? f2bf(W[k * N + n]) : (u16)0;
  }
  lo.x = v[0]; lo.y = v[1]; lo.z = v[2]; lo.w = v[3];
  hi.x = v[4]; hi.y = v[5]; hi.z = v[6]; hi.w = v[7];
  ushort4* dst = (ushort4*)&out[(size_t)t * 8];
  dst[0] = lo; dst[1] = hi;
}

// ---- counting sort of edges by receiver (graph fixed across all 3 steps).
__global__ void hist_kernel(const int* __restrict__ rcv, int* __restrict__ cnt) {
  int i = blockIdx.x * blockDim.x + threadIdx.x;
  if (i < NE) atomicAdd(&cnt[rcv[i]], 1);
}

// Chunked COALESCED block scan (r5).
__launch_bounds__(1024)
__global__ void scan_kernel(const int* __restrict__ cnt, int* __restrict__ rowptr,
                            int* __restrict__ cursor) {
  __shared__ int wsum[16];
  const int t = threadIdx.x;
  const int lane = t & 63;
  const int wid = t >> 6;
  int carry = 0;
  for (int base = 0; base < NN; base += 1024) {
    const int i = base + t;
    int v = (i < NN) ? cnt[i] : 0;
    int x = v;
#pragma unroll
    for (int off = 1; off < 64; off <<= 1) {
      int y = __shfl_up(x, off);
      if (lane >= off) x += y;
    }
    if (lane == 63) wsum[wid] = x;
    __syncthreads();
    if (wid == 0 && lane < 16) {
      int s = wsum[lane];
#pragma unroll
      for (int off = 1; off < 16; off <<= 1) {
        int y = __shfl_up(s, off);
        if (lane >= off) s += y;
      }
      wsum[lane] = s;   // inclusive wave prefix
    }
    __syncthreads();
    const int excl = carry + (wid > 0 ? wsum[wid - 1] : 0) + (x - v);
    if (i < NN) { rowptr[i] = excl; cursor[i] = excl; }
    carry += wsum[15];  // chunk total (uniform across block)
    __syncthreads();    // protect wsum reuse next chunk
  }
  if (t == 0) rowptr[NN] = NE;
}

__global__ void scatter_kernel(const int* __restrict__ snd, const int* __restrict__ rcv,
                               int* __restrict__ cursor, int* __restrict__ ssnd,
                               int* __restrict__ srcv) {
  int i = blockIdx.x * blockDim.x + threadIdx.x;
  if (i >= NE) return;
  int r = rcv[i];
  int p = atomicAdd(&cursor[r], 1);
  ssnd[p] = snd[i];
  srcv[p] = r;
}

__global__ void embed_kernel(const float* __restrict__ nodes, const float* __restrict__ w,
                             const float* __restrict__ b, float* __restrict__ h,
                             u16* __restrict__ hbf) {
  int gid = blockIdx.x * blockDim.x + threadIdx.x;
  if (gid >= NN * LAT) return;
  int n = gid >> 6, j = gid & 63;
  float acc = b[j];
#pragma unroll
  for (int k = 0; k < INF; ++k)
    acc = fmaf(nodes[n * INF + k], w[k * LAT + j], acc);
  h[gid] = acc;
  hbf[gid] = f2bf(acc);
}

// ---- wave-per-node CSR segment-sum over receiver-sorted ebuf (r5).
__launch_bounds__(256)
__global__ void agg_kernel(const u16* __restrict__ ebuf, const int* __restrict__ rowptr,
                           u16* __restrict__ recvbf) {
  const int gid = blockIdx.x * blockDim.x + threadIdx.x;
  const int node = gid >> 6;
  if (node >= NN) return;
  const int lane = threadIdx.x & 63;
  const int sub = lane >> 3;
  const int c8 = (lane & 7) * 8;
  const int e0 = rowptr[node], e1 = rowptr[node + 1];
  float a[8] = {0.f, 0.f, 0.f, 0.f, 0.f, 0.f, 0.f, 0.f};
  for (int e = e0 + sub; e < e1; e += 8) {
    uint4 v = *(const uint4*)&ebuf[(size_t)e * 64 + c8];
    a[0] += blo(v.x); a[1] += bhi(v.x);
    a[2] += blo(v.y); a[3] += bhi(v.y);
    a[4] += blo(v.z); a[5] += bhi(v.z);
    a[6] += blo(v.w); a[7] += bhi(v.w);
  }
#pragma unroll
  for (int k = 0; k < 8; ++k) {
    a[k] += __shfl_xor(a[k], 8);
    a[k] += __shfl_xor(a[k], 16);
    a[k] += __shfl_xor(a[k], 32);
  }
  if (sub == 0) {
    ushort4 p0, p1;
    p0.x = f2bf(a[0]); p0.y = f2bf(a[1]); p0.z = f2bf(a[2]); p0.w = f2bf(a[3]);
    p1.x = f2bf(a[4]); p1.y = f2bf(a[5]); p1.z = f2bf(a[6]); p1.w = f2bf(a[7]);
    *(ushort4*)&recvbf[(size_t)node * 64 + c8]     = p0;
    *(ushort4*)&recvbf[(size_t)node * 64 + c8 + 4] = p1;
  }
}

// ---- MFMA edge MLP. r8: M=64 edges/block (was 32). L2 weight traffic was
// STILL the ceiling (VGPR=120 proves r3's "hoist" never held weights in regs;
// 3.69 GB/dispatch ~= 107us at L2 34.5 TB/s == measured 103us). Each weight
// fragment read now serves 64 rows instead of 16: wave w owns ALL 4 row-tiles
// x cols [w*32,(w+1)*32) in phase 1 and col-tile w in phase 2. Weight reads
// per tile: 7x2+4=18/wave (was 36), tiles halved -> L2 weight traffic /4.
// Epilogues, gathers, prefetch, barriers: r5 form (r6/r7 swap reverted --
// regressed via ds_write_b64 4-way bank conflicts).
// K layout FIRST: [s 64][r 64][g 16|pad] = 160 (KC=5, AF=4)
//          else : [e 64][s 64][r 64][g 16|pad] = 224 (KC=7, AF=6)
template <int KC, bool FIRST>
__launch_bounds__(256, 2)
__global__ void edge_mfma(const u16* __restrict__ hbf, u16* __restrict__ ebuf,
                          const int* __restrict__ snd, const int* __restrict__ rcv,
                          const u16* __restrict__ gpad,
                          const u16* __restrict__ w1p, const float* __restrict__ b1,
                          const u16* __restrict__ w2p, const float* __restrict__ b2) {
  __shared__ __align__(16) u16 hid[64 * 136];
  __shared__ __align__(16) u16 easm[64 * 72];

  const int tid = threadIdx.x;
  const int lane = tid & 63;
  const int w = tid >> 6;
  const int l15 = lane & 15;
  const int q = lane >> 4;
  const int NTILE = NE / 64;
  constexpr int AF = FIRST ? 4 : 6;  // per-row input fragments (g loop-invariant)

  float bb1[2];
  bb1[0] = b1[(2 * w) * 16 + l15];
  bb1[1] = b1[(2 * w + 1) * 16 + l15];
  const float bb2 = b2[w * 16 + l15];
  const bf16x8 gfrag = *(const bf16x8*)&gpad[q * 8];

  // ---- A pipeline: acur[rt] = tile t's fragments for edge rt*16+l15;
  //      s_cur/r_cur hold t+1's indices.
  bf16x8 acur[4][AF];
  int s_cur[4], r_cur[4];
  {
    const int t0 = blockIdx.x;
    if (t0 < NTILE) {
#pragma unroll
      for (int rt = 0; rt < 4; ++rt) {
        const int eg0 = t0 * 64 + rt * 16 + l15;
        const int s0 = snd[eg0], r0 = rcv[eg0];
        if (!FIRST) {
#pragma unroll
          for (int kc = 0; kc < 2; ++kc)
            acur[rt][kc] = *(const bf16x8*)&ebuf[(size_t)eg0 * 64 + kc * 32 + q * 8];
        }
#pragma unroll
        for (int kc = 0; kc < 2; ++kc)
          acur[rt][(FIRST ? 0 : 2) + kc] = *(const bf16x8*)&hbf[s0 * 64 + kc * 32 + q * 8];
#pragma unroll
        for (int kc = 0; kc < 2; ++kc)
          acur[rt][(FIRST ? 2 : 4) + kc] = *(const bf16x8*)&hbf[r0 * 64 + kc * 32 + q * 8];
      }
      const int t1 = t0 + gridDim.x;
      if (t1 < NTILE) {
#pragma unroll
        for (int rt = 0; rt < 4; ++rt) {
          s_cur[rt] = snd[t1 * 64 + rt * 16 + l15];
          r_cur[rt] = rcv[t1 * 64 + rt * 16 + l15];
        }
      }
    }
  }

  for (int tile = blockIdx.x; tile < NTILE; tile += gridDim.x) {
    const int ebase = tile * 64;

    // --- phase 1: hid = gelu(in @ W1 + b1)  [64 x 128]
    // each W1 fragment read serves 4 row-tiles (the traffic /4 lever)
    f32x4 acc[4][2];
#pragma unroll
    for (int rt = 0; rt < 4; ++rt)
#pragma unroll
      for (int i = 0; i < 2; ++i)
        acc[rt][i] = (f32x4){bb1[i], bb1[i], bb1[i], bb1[i]};
#pragma unroll
    for (int kc = 0; kc < KC; ++kc) {
      bf16x8 bw0 = *(const bf16x8*)&w1p[(size_t)((kc * 8 + 2 * w) * 64 + lane) * 8];
      bf16x8 bw1 = *(const bf16x8*)&w1p[(size_t)((kc * 8 + 2 * w + 1) * 64 + lane) * 8];
#pragma unroll
      for (int rt = 0; rt < 4; ++rt) {
        bf16x8 a = (kc < AF) ? acur[rt][kc] : gfrag;
        acc[rt][0] = __builtin_amdgcn_mfma_f32_16x16x32_bf16(a, bw0, acc[rt][0], 0, 0, 0);
        acc[rt][1] = __builtin_amdgcn_mfma_f32_16x16x32_bf16(a, bw1, acc[rt][1], 0, 0, 0);
      }
    }

    // --- prefetch next tile's A rows (reuses acur; lands during phase2+store)
    {
      const int tn = tile + gridDim.x;
      if (tn < NTILE) {
#pragma unroll
        for (int rt = 0; rt < 4; ++rt) {
          const int egn = tn * 64 + rt * 16 + l15;
          const int soffn = s_cur[rt] * 64;
          const int roffn = r_cur[rt] * 64;
          if (!FIRST) {
#pragma unroll
            for (int kc = 0; kc < 2; ++kc)
              acur[rt][kc] = *(const bf16x8*)&ebuf[(size_t)egn * 64 + kc * 32 + q * 8];
          }
#pragma unroll
          for (int kc = 0; kc < 2; ++kc)
            acur[rt][(FIRST ? 0 : 2) + kc] = *(const bf16x8*)&hbf[soffn + kc * 32 + q * 8];
#pragma unroll
          for (int kc = 0; kc < 2; ++kc)
            acur[rt][(FIRST ? 2 : 4) + kc] = *(const bf16x8*)&hbf[roffn + kc * 32 + q * 8];
        }
        const int tn2 = tn + gridDim.x;
        if (tn2 < NTILE) {
#pragma unroll
          for (int rt = 0; rt < 4; ++rt) {
            s_cur[rt] = snd[tn2 * 64 + rt * 16 + l15];
            r_cur[rt] = rcv[tn2 * 64 + rt * 16 + l15];
          }
        }
      }
    }

    // --- phase-1 epilogue: gelu -> hid (LDS, r5 scatter form)
#pragma unroll
    for (int rt = 0; rt < 4; ++rt)
#pragma unroll
      for (int i = 0; i < 2; ++i) {
        const int col = (2 * w + i) * 16 + l15;
#pragma unroll
        for (int r4 = 0; r4 < 4; ++r4) {
          const int row = rt * 16 + q * 4 + r4;
          hid[row * 136 + col] = f2bf(gelu(acc[rt][i][r4]));
        }
      }
    // barrier WITHOUT vmcnt drain (prefetch stays in flight)
    asm volatile("s_waitcnt lgkmcnt(0)" ::: "memory");
    __builtin_amdgcn_s_barrier();

    // --- phase 2: out = hid @ W2 + b2   [64 x 64] -> easm (bf16)
    {
      f32x4 acc2[4];
#pragma unroll
      for (int rt = 0; rt < 4; ++rt) acc2[rt] = (f32x4){bb2, bb2, bb2, bb2};
#pragma unroll
      for (int kc = 0; kc < 4; ++kc) {
        bf16x8 bw = *(const bf16x8*)&w2p[(size_t)((kc * 4 + w) * 64 + lane) * 8];
#pragma unroll
        for (int rt = 0; rt < 4; ++rt) {
          bf16x8 a = *(const bf16x8*)&hid[(rt * 16 + l15) * 136 + kc * 32 + q * 8];
          acc2[rt] = __builtin_amdgcn_mfma_f32_16x16x32_bf16(a, bw, acc2[rt], 0, 0, 0);
        }
      }
#pragma unroll
      for (int rt = 0; rt < 4; ++rt) {
        const int col = w * 16 + l15;
#pragma unroll
        for (int r4 = 0; r4 < 4; ++r4) {
          const int row = rt * 16 + q * 4 + r4;
          easm[row * 72 + col] = f2bf(acc2[rt][r4]);
        }
      }
    }
    asm volatile("s_waitcnt lgkmcnt(0)" ::: "memory");
    __builtin_amdgcn_s_barrier();
    // --- coalesced e_out write: 512 x uint4 = 64 rows x 128B
#pragma unroll
    for (int part = 0; part < 2; ++part) {
      const int idx = part * 256 + tid;
      const int r = idx >> 3, c = (idx & 7) * 8;
      ((uint4*)&ebuf[(size_t)ebase * 64])[idx] = *(const uint4*)&easm[r * 72 + c];
    }
  }
}

// ---- MFMA node MLP + skip + LayerNorm (r5 form). recv read as bf16 from
// agg_kernel output.
__launch_bounds__(256)
__global__ void node_mfma(float* __restrict__ h, u16* __restrict__ hbf,
                          const u16* __restrict__ recvbf,
                          const u16* __restrict__ gpad,
                          const u16* __restrict__ w1p, const float* __restrict__ b1,
                          const u16* __restrict__ w2p, const float* __restrict__ b2,
                          const float* __restrict__ lns, const float* __restrict__ lnb) {
  __shared__ __align__(16) u16 hid[32 * 136];
  __shared__ __align__(16) float outs[32 * 68];

  const int tid = threadIdx.x;
  const int lane = tid & 63;
  const int w = tid >> 6;
  const int l15 = lane & 15;
  const int q = lane >> 4;
  const int mr = w & 1;
  const int ntb1 = (w >> 1) * 4;
  const int ntb2 = (w >> 1) * 2;
  const int arow = mr * 16 + l15;

  float bb1[4], bb2[2];
#pragma unroll
  for (int i = 0; i < 4; ++i) bb1[i] = b1[(ntb1 + i) * 16 + l15];
#pragma unroll
  for (int i = 0; i < 2; ++i) bb2[i] = b2[(ntb2 + i) * 16 + l15];

  const int nrow = tid >> 3;
  const int jc = (tid & 7) * 8;
  float sc8[8], bi8[8];
#pragma unroll
  for (int k = 0; k < 8; ++k) { sc8[k] = lns[jc + k]; bi8[k] = lnb[jc + k]; }

  const int NT = (NN + 31) / 32;
  for (int tile = blockIdx.x; tile < NT; tile += gridDim.x) {
    const int nbase = tile * 32;
    const int na = min(nbase + arow, NN - 1) * 64;   // clamped A-row offset

    // --- phase 1
    {
      f32x4 acc[4];
#pragma unroll
      for (int i = 0; i < 4; ++i) acc[i] = (f32x4){bb1[i], bb1[i], bb1[i], bb1[i]};
#pragma unroll
      for (int kc = 0; kc < 5; ++kc) {
        bf16x8 a;
        if (kc < 2) {
          a = *(const bf16x8*)&hbf[na + kc * 32 + q * 8];
        } else if (kc < 4) {
          a = *(const bf16x8*)&recvbf[na + (kc - 2) * 32 + q * 8];
        } else {
          a = *(const bf16x8*)&gpad[q * 8];
        }
#pragma unroll
        for (int i = 0; i < 4; ++i) {
          bf16x8 b = *(const bf16x8*)&w1p[(size_t)((kc * 8 + ntb1 + i) * 64 + lane) * 8];
          acc[i] = __builtin_amdgcn_mfma_f32_16x16x32_bf16(a, b, acc[i], 0, 0, 0);
        }
      }
#pragma unroll
      for (int i = 0; i < 4; ++i) {
        const int col = (ntb1 + i) * 16 + l15;
#pragma unroll
        for (int r4 = 0; r4 < 4; ++r4) {
          const int row = mr * 16 + q * 4 + r4;
          hid[row * 136 + col] = f2bf(gelu(acc[i][r4]));
        }
      }
    }
    __syncthreads();
    // --- phase 2: upd = hid @ W2 + b2 -> outs (fp32 LDS)
    {
      f32x4 acc[2];
#pragma unroll
      for (int i = 0; i < 2; ++i) acc[i] = (f32x4){bb2[i], bb2[i], bb2[i], bb2[i]};
#pragma unroll
      for (int kc = 0; kc < 4; ++kc) {
        bf16x8 a = *(const bf16x8*)&hid[arow * 136 + kc * 32 + q * 8];
#pragma unroll
        for (int i = 0; i < 2; ++i) {
          bf16x8 b = *(const bf16x8*)&w2p[(size_t)((kc * 4 + ntb2 + i) * 64 + lane) * 8];
          acc[i] = __builtin_amdgcn_mfma_f32_16x16x32_bf16(a, b, acc[i], 0, 0, 0);
        }
      }
#pragma unroll
      for (int i = 0; i < 2; ++i) {
        const int col = (ntb2 + i) * 16 + l15;
#pragma unroll
        for (int r4 = 0; r4 < 4; ++r4) {
          const int row = mr * 16 + q * 4 + r4;
          outs[row * 68 + col] = acc[i][r4];
        }
      }
    }
    __syncthreads();
    // --- skip + LayerNorm: 8 threads per node row, 8 cols each
    {
      const int n = nbase + nrow;
      if (n < NN) {
        float x[8];
        float4 hv0 = *(const float4*)&h[n * 64 + jc];
        float4 hv1 = *(const float4*)&h[n * 64 + jc + 4];
        x[0] = hv0.x + outs[nrow * 68 + jc + 0];
        x[1] = hv0.y + outs[nrow * 68 + jc + 1];
        x[2] = hv0.z + outs[nrow * 68 + jc + 2];
        x[3] = hv0.w + outs[nrow * 68 + jc + 3];
        x[4] = hv1.x + outs[nrow * 68 + jc + 4];
        x[5] = hv1.y + outs[nrow * 68 + jc + 5];
        x[6] = hv1.z + outs[nrow * 68 + jc + 6];
        x[7] = hv1.w + outs[nrow * 68 + jc + 7];
        float s = 0.f, qq = 0.f;
#pragma unroll
        for (int k = 0; k < 8; ++k) { s += x[k]; qq += x[k] * x[k]; }
#pragma unroll
        for (int off = 1; off < 8; off <<= 1) {
          s += __shfl_xor(s, off);
          qq += __shfl_xor(qq, off);
        }
        float mean = s * (1.0f / 64.0f);
        float var = fmaxf(qq * (1.0f / 64.0f) - mean * mean, 0.0f);
        float rstd = rsqrtf(var + 1e-6f);
        float o[8];
        ushort4 ob0, ob1;
#pragma unroll
        for (int k = 0; k < 8; ++k) o[k] = (x[k] - mean) * rstd * sc8[k] + bi8[k];
        *(float4*)&h[n * 64 + jc]     = make_float4(o[0], o[1], o[2], o[3]);
        *(float4*)&h[n * 64 + jc + 4] = make_float4(o[4], o[5], o[6], o[7]);
        ob0.x = f2bf(o[0]); ob0.y = f2bf(o[1]); ob0.z = f2bf(o[2]); ob0.w = f2bf(o[3]);
        ob1.x = f2bf(o[4]); ob1.y = f2bf(o[5]); ob1.z = f2bf(o[6]); ob1.w = f2bf(o[7]);
        *(ushort4*)&hbf[n * 64 + jc]     = ob0;
        *(ushort4*)&hbf[n * 64 + jc + 4] = ob1;
      }
    }
    __syncthreads();   // protect hid/outs reuse next tile
  }
}

// Output dtype: float32 (reference returns fp32).
__global__ void decode_kernel(const float* __restrict__ h, const float* __restrict__ w,
                              const float* __restrict__ b, float* __restrict__ out) {
  int gid = blockIdx.x * blockDim.x + threadIdx.x;
  if (gid >= NN * INF) return;
  int n = gid / 7, f = gid % 7;
  float acc = b[f];
#pragma unroll
  for (int k = 0; k < LAT; ++k)
    acc = fmaf(h[n * 64 + k], w[k * 7 + f], acc);
  out[gid] = acc;
}

extern "C" void kernel_launch(void* const* d_in, const int* in_sizes, int n_in,
                              void* d_out, int out_size, void* d_ws, size_t ws_size,
                              hipStream_t stream) {
  const float* nodes = (const float*)d_in[0];
  const int* senders = (const int*)d_in[1];
  const int* recvrs  = (const int*)d_in[2];
  const float* g     = (const float*)d_in[3];
  const float* emb_w = (const float*)d_in[4];
  const float* emb_b = (const float*)d_in[5];
  const float* ew1f  = (const float*)d_in[6];
  const float* ew1r  = (const float*)d_in[7];
  const float* eb1   = (const float*)d_in[8];
  const float* ew2   = (const float*)d_in[9];
  const float* eb2   = (const float*)d_in[10];
  const float* nw1   = (const float*)d_in[11];
  const float* nb1   = (const float*)d_in[12];
  const float* nw2   = (const float*)d_in[13];
  const float* nb2   = (const float*)d_in[14];
  const float* lns   = (const float*)d_in[15];
  const float* lnb   = (const float*)d_in[16];
  const float* dw    = (const float*)d_in[17];
  const float* db    = (const float*)d_in[18];

  char* cur = (char*)d_ws;
  float* h      = (float*)cur;  cur += (size_t)NN * LAT * 4;        // 12.8 MB
  u16*   ebuf   = (u16*)cur;    cur += (size_t)NE * LAT * 2;        // 102.4 MB
  u16*   hbf    = (u16*)cur;    cur += (size_t)NN * LAT * 2;        // 6.4 MB
  u16*   recvbf = (u16*)cur;    cur += (size_t)NN * LAT * 2;        // 6.4 MB
  u16*   ew1p[3]; for (int t = 0; t < 3; ++t) { ew1p[t] = (u16*)cur; cur += 7 * 8 * 64 * 8 * 2; }
  u16*   ew2p[3]; for (int t = 0; t < 3; ++t) { ew2p[t] = (u16*)cur; cur += 4 * 4 * 64 * 8 * 2; }
  u16*   nw1p[3]; for (int t = 0; t < 3; ++t) { nw1p[t] = (u16*)cur; cur += 5 * 8 * 64 * 8 * 2; }
  u16*   nw2p[3]; for (int t = 0; t < 3; ++t) { nw2p[t] = (u16*)cur; cur += 4 * 4 * 64 * 8 * 2; }
  u16*   gpad   = (u16*)cur;    cur += 256;
  int*   cnt    = (int*)cur;    cur += ((size_t)NN * 4 + 255) & ~(size_t)255;
  int*   cursor = (int*)cur;    cur += ((size_t)NN * 4 + 255) & ~(size_t)255;
  int*   rowptr = (int*)cur;    cur += ((size_t)(NN + 1) * 4 + 255) & ~(size_t)255;
  int*   ssnd   = (int*)cur;    cur += (size_t)NE * 4;              // 3.2 MB
  int*   srcv   = (int*)cur;    cur += (size_t)NE * 4;              // 3.2 MB

  // one-time receiver counting sort (graph fixed across steps)
  hipMemsetAsync(cnt, 0, (size_t)NN * 4, stream);
  hist_kernel<<<(NE + 255) / 256, 256, 0, stream>>>(recvrs, cnt);
  scan_kernel<<<1, 1024, 0, stream>>>(cnt, rowptr, cursor);
  scatter_kernel<<<(NE + 255) / 256, 256, 0, stream>>>(senders, recvrs, cursor, ssnd, srcv);

  // single consolidated pre-pack dispatch (13 jobs)
  PackJobs J;
  J.src[0] = ew1f;                       J.dst[0] = ew1p[0]; J.K[0] = 144; J.N[0] = 128; J.KC[0] = 5;
  J.src[1] = ew1r;                       J.dst[1] = ew1p[1]; J.K[1] = 208; J.N[1] = 128; J.KC[1] = 7;
  J.src[2] = ew1r + (size_t)208 * 128;   J.dst[2] = ew1p[2]; J.K[2] = 208; J.N[2] = 128; J.KC[2] = 7;
  for (int t = 0; t < 3; ++t) {
    J.src[3 + t] = ew2 + (size_t)t * 128 * 64;  J.dst[3 + t] = ew2p[t]; J.K[3 + t] = 128; J.N[3 + t] = 64; J.KC[3 + t] = 4;
    J.src[6 + t] = nw1 + (size_t)t * 144 * 128; J.dst[6 + t] = nw1p[t]; J.K[6 + t] = 144; J.N[6 + t] = 128; J.KC[6 + t] = 5;
    J.src[9 + t] = nw2 + (size_t)t * 128 * 64;  J.dst[9 + t] = nw2p[t]; J.K[9 + t] = 128; J.N[9 + t] = 64; J.KC[9 + t] = 4;
  }
  J.src[12] = g; J.dst[12] = gpad; J.K[12] = 0; J.N[12] = 0; J.KC[12] = 0;
  pack_all<<<dim3(16, 13), 256, 0, stream>>>(J);

  embed_kernel<<<(NN * LAT + 255) / 256, 256, 0, stream>>>(nodes, emb_w, emb_b, h, hbf);

  for (int t = 0; t < 3; ++t) {
    if (t == 0)
      edge_mfma<5, true><<<2084, 256, 0, stream>>>(hbf, ebuf,
          ssnd, srcv, gpad, ew1p[0], eb1, ew2p[0], eb2);
    else
      edge_mfma<7, false><<<2084, 256, 0, stream>>>(hbf, ebuf,
          ssnd, srcv, gpad, ew1p[t], eb1 + t * 128, ew2p[t], eb2 + t * 64);
    agg_kernel<<<(NN * 64 + 255) / 256, 256, 0, stream>>>(ebuf, rowptr, recvbf);
    node_mfma<<<1563, 256, 0, stream>>>(h, hbf, recvbf, gpad,
        nw1p[t], nb1 + t * 128, nw2p[t], nb2 + t * 64,
        lns + t * 64, lnb + t * 64);
  }

  decode_kernel<<<(NN * INF + 255) / 256, 256, 0, stream>>>(h, dw, db, (float*)d_out);
}

// Round 9
// 763.768 us; speedup vs baseline: 1.0521x; 1.0521x over previous
//
#include <hip/hip_runtime.h>

#define NN 50000
#define NE 800000
#define INF 7
#define GD 16
#define LAT 64
#define HID 128

typedef unsigned short u16;
typedef __attribute__((ext_vector_type(8))) __bf16 bf16x8;
typedef __attribute__((ext_vector_type(4))) float f32x4;

__device__ __forceinline__ float bf2f(u16 u) {
  union { unsigned int i; float f; } v; v.i = ((unsigned int)u) << 16; return v.f;
}
__device__ __forceinline__ float blo(unsigned int u) {
  union { unsigned int i; float f; } v; v.i = u << 16; return v.f;
}
__device__ __forceinline__ float bhi(unsigned int u) {
  union { unsigned int i; float f; } v; v.i = u & 0xffff0000u; return v.f;
}
__device__ __forceinline__ u16 f2bf(float f) {
  union { float f; unsigned int i; } v; v.f = f;
  unsigned int x = v.i;
  return (u16)((x + 0x7fffu + ((x >> 16) & 1u)) >> 16);
}
// jax.nn.gelu approximate (tanh form) as x*sigmoid(2z) with v_rcp (r11-verified).
__device__ __forceinline__ float gelu(float x) {
  float u = x * x;
  float p = fmaf(0.044715f * u, x, x);
  float e = __expf(-1.5957691216057308f * p);
  return x * __builtin_amdgcn_rcpf(e + 1.0f);
}

// ---- consolidated weight pre-pack: 13 jobs in one dispatch.
struct PackJobs {
  const float* src[13];
  u16* dst[13];
  int K[13];
  int N[13];
  int KC[13];
};

__global__ void pack_all(PackJobs J) {
  const int j = blockIdx.y;
  const int KC = J.KC[j];
  const float* W = J.src[j];
  u16* out = J.dst[j];
  int t = blockIdx.x * blockDim.x + threadIdx.x;
  if (KC == 0) {            // gpad job
    if (t < 32) out[t] = (t < GD) ? f2bf(W[t]) : (u16)0;
    return;
  }
  const int K = J.K[j], N = J.N[j];
  const int NT = N >> 4;
  if (t >= KC * NT * 64) return;
  int l = t & 63;
  int nt = (t >> 6) % NT;
  int kc = t / (64 * NT);
  int n = nt * 16 + (l & 15);
  int kbase = kc * 32 + (l >> 4) * 8;
  ushort4 lo, hi;
  u16 v[8];
#pragma unroll
  for (int jj = 0; jj < 8; ++jj) {
    int k = kbase + jj;
    v[jj] = (k < K) ? f2bf(W[k * N + n]) : (u16)0;
  }
  lo.x = v[0]; lo.y = v[1]; lo.z = v[2]; lo.w = v[3];
  hi.x = v[4]; hi.y = v[5]; hi.z = v[6]; hi.w = v[7];
  ushort4* dst = (ushort4*)&out[(size_t)t * 8];
  dst[0] = lo; dst[1] = hi;
}

// ---- counting sort of edges by receiver (graph fixed across all 3 steps).
__global__ void hist_kernel(const int* __restrict__ rcv, int* __restrict__ cnt) {
  int i = blockIdx.x * blockDim.x + threadIdx.x;
  if (i < NE) atomicAdd(&cnt[rcv[i]], 1);
}

// Chunked COALESCED block scan (r5).
__launch_bounds__(1024)
__global__ void scan_kernel(const int* __restrict__ cnt, int* __restrict__ rowptr,
                            int* __restrict__ cursor) {
  __shared__ int wsum[16];
  const int t = threadIdx.x;
  const int lane = t & 63;
  const int wid = t >> 6;
  int carry = 0;
  for (int base = 0; base < NN; base += 1024) {
    const int i = base + t;
    int v = (i < NN) ? cnt[i] : 0;
    int x = v;
#pragma unroll
    for (int off = 1; off < 64; off <<= 1) {
      int y = __shfl_up(x, off);
      if (lane >= off) x += y;
    }
    if (lane == 63) wsum[wid] = x;
    __syncthreads();
    if (wid == 0 && lane < 16) {
      int s = wsum[lane];
#pragma unroll
      for (int off = 1; off < 16; off <<= 1) {
        int y = __shfl_up(s, off);
        if (lane >= off) s += y;
      }
      wsum[lane] = s;   // inclusive wave prefix
    }
    __syncthreads();
    const int excl = carry + (wid > 0 ? wsum[wid - 1] : 0) + (x - v);
    if (i < NN) { rowptr[i] = excl; cursor[i] = excl; }
    carry += wsum[15];  // chunk total (uniform across block)
    __syncthreads();    // protect wsum reuse next chunk
  }
  if (t == 0) rowptr[NN] = NE;
}

__global__ void scatter_kernel(const int* __restrict__ snd, const int* __restrict__ rcv,
                               int* __restrict__ cursor, int* __restrict__ ssnd,
                               int* __restrict__ srcv) {
  int i = blockIdx.x * blockDim.x + threadIdx.x;
  if (i >= NE) return;
  int r = rcv[i];
  int p = atomicAdd(&cursor[r], 1);
  ssnd[p] = snd[i];
  srcv[p] = r;
}

__global__ void embed_kernel(const float* __restrict__ nodes, const float* __restrict__ w,
                             const float* __restrict__ b, float* __restrict__ h,
                             u16* __restrict__ hbf) {
  int gid = blockIdx.x * blockDim.x + threadIdx.x;
  if (gid >= NN * LAT) return;
  int n = gid >> 6, j = gid & 63;
  float acc = b[j];
#pragma unroll
  for (int k = 0; k < INF; ++k)
    acc = fmaf(nodes[n * INF + k], w[k * LAT + j], acc);
  h[gid] = acc;
  hbf[gid] = f2bf(acc);
}

// ---- wave-per-node CSR segment-sum over receiver-sorted ebuf (r5).
__launch_bounds__(256)
__global__ void agg_kernel(const u16* __restrict__ ebuf, const int* __restrict__ rowptr,
                           u16* __restrict__ recvbf) {
  const int gid = blockIdx.x * blockDim.x + threadIdx.x;
  const int node = gid >> 6;
  if (node >= NN) return;
  const int lane = threadIdx.x & 63;
  const int sub = lane >> 3;
  const int c8 = (lane & 7) * 8;
  const int e0 = rowptr[node], e1 = rowptr[node + 1];
  float a[8] = {0.f, 0.f, 0.f, 0.f, 0.f, 0.f, 0.f, 0.f};
  for (int e = e0 + sub; e < e1; e += 8) {
    uint4 v = *(const uint4*)&ebuf[(size_t)e * 64 + c8];
    a[0] += blo(v.x); a[1] += bhi(v.x);
    a[2] += blo(v.y); a[3] += bhi(v.y);
    a[4] += blo(v.z); a[5] += bhi(v.z);
    a[6] += blo(v.w); a[7] += bhi(v.w);
  }
#pragma unroll
  for (int k = 0; k < 8; ++k) {
    a[k] += __shfl_xor(a[k], 8);
    a[k] += __shfl_xor(a[k], 16);
    a[k] += __shfl_xor(a[k], 32);
  }
  if (sub == 0) {
    ushort4 p0, p1;
    p0.x = f2bf(a[0]); p0.y = f2bf(a[1]); p0.z = f2bf(a[2]); p0.w = f2bf(a[3]);
    p1.x = f2bf(a[4]); p1.y = f2bf(a[5]); p1.z = f2bf(a[6]); p1.w = f2bf(a[7]);
    *(ushort4*)&recvbf[(size_t)node * 64 + c8]     = p0;
    *(ushort4*)&recvbf[(size_t)node * 64 + c8 + 4] = p1;
  }
}

// ---- MFMA edge MLP. r9: M=64 edges/block KEPT (weight-fragment reuse x4,
// the L1/L2 traffic lever), but the r8 register-held A pipeline REMOVED --
// acur[4][6]=96 live VGPRs under the 128 cap forced scratch spills (r8: all
// pipes collapsed together, SGPR 32->112). A-fragments now load ON DEMAND
// inside phase 1 (kc x rt, addresses from 12 offset VGPRs); only next-tile
// INDICES are prefetched (8 VGPRs). 8 independent MFMAs per kc-step + 2
// blocks/CU hide the L2-hit latency. All 4 waves read the same A rows -> L1
// serves the duplication.
// K layout FIRST: [s 64][r 64][g 16|pad] = 160 (KC=5, AF=4)
//          else : [e 64][s 64][r 64][g 16|pad] = 224 (KC=7, AF=6)
template <int KC, bool FIRST>
__launch_bounds__(256, 2)
__global__ void edge_mfma(const u16* __restrict__ hbf, u16* __restrict__ ebuf,
                          const int* __restrict__ snd, const int* __restrict__ rcv,
                          const u16* __restrict__ gpad,
                          const u16* __restrict__ w1p, const float* __restrict__ b1,
                          const u16* __restrict__ w2p, const float* __restrict__ b2) {
  __shared__ __align__(16) u16 hid[64 * 136];
  __shared__ __align__(16) u16 easm[64 * 72];

  const int tid = threadIdx.x;
  const int lane = tid & 63;
  const int w = tid >> 6;
  const int l15 = lane & 15;
  const int q = lane >> 4;
  const int NTILE = NE / 64;
  constexpr int AF = FIRST ? 4 : 6;

  float bb1[2];
  bb1[0] = b1[(2 * w) * 16 + l15];
  bb1[1] = b1[(2 * w + 1) * 16 + l15];
  const float bb2 = b2[w * 16 + l15];
  const bf16x8 gfrag = *(const bf16x8*)&gpad[q * 8];

  // index pipeline: s_cur/r_cur hold the CURRENT tile's indices (prefetched)
  int s_cur[4], r_cur[4];
  {
    const int t0 = blockIdx.x;
    if (t0 < NTILE) {
#pragma unroll
      for (int rt = 0; rt < 4; ++rt) {
        s_cur[rt] = snd[t0 * 64 + rt * 16 + l15];
        r_cur[rt] = rcv[t0 * 64 + rt * 16 + l15];
      }
    }
  }

  for (int tile = blockIdx.x; tile < NTILE; tile += gridDim.x) {
    const int ebase = tile * 64;
    int soff[4], roff[4];
#pragma unroll
    for (int rt = 0; rt < 4; ++rt) {
      soff[rt] = s_cur[rt] * 64;
      roff[rt] = r_cur[rt] * 64;
    }

    // prefetch next tile's indices (hides under phase-1 compute)
    {
      const int tn = tile + gridDim.x;
      if (tn < NTILE) {
#pragma unroll
        for (int rt = 0; rt < 4; ++rt) {
          s_cur[rt] = snd[tn * 64 + rt * 16 + l15];
          r_cur[rt] = rcv[tn * 64 + rt * 16 + l15];
        }
      }
    }

    // --- phase 1: hid = gelu(in @ W1 + b1)  [64 x 128]
    // wave w covers ALL 4 row-tiles x col-tiles {2w, 2w+1}: each weight
    // fragment read serves 64 rows (the /4 traffic lever). A-frags load
    // on demand -- short-lived registers, no spill.
    f32x4 acc[4][2];
#pragma unroll
    for (int rt = 0; rt < 4; ++rt) {
      acc[rt][0] = (f32x4){bb1[0], bb1[0], bb1[0], bb1[0]};
      acc[rt][1] = (f32x4){bb1[1], bb1[1], bb1[1], bb1[1]};
    }
#pragma unroll
    for (int kc = 0; kc < KC; ++kc) {
      bf16x8 bw0 = *(const bf16x8*)&w1p[(size_t)((kc * 8 + 2 * w) * 64 + lane) * 8];
      bf16x8 bw1 = *(const bf16x8*)&w1p[(size_t)((kc * 8 + 2 * w + 1) * 64 + lane) * 8];
#pragma unroll
      for (int rt = 0; rt < 4; ++rt) {
        bf16x8 a;
        if (kc >= AF) {
          a = gfrag;
        } else if (FIRST) {
          a = (kc < 2) ? *(const bf16x8*)&hbf[soff[rt] + kc * 32 + q * 8]
                       : *(const bf16x8*)&hbf[roff[rt] + (kc - 2) * 32 + q * 8];
        } else {
          a = (kc < 2) ? *(const bf16x8*)&ebuf[(size_t)(ebase + rt * 16 + l15) * 64 + kc * 32 + q * 8]
            : (kc < 4) ? *(const bf16x8*)&hbf[soff[rt] + (kc - 2) * 32 + q * 8]
                       : *(const bf16x8*)&hbf[roff[rt] + (kc - 4) * 32 + q * 8];
        }
        acc[rt][0] = __builtin_amdgcn_mfma_f32_16x16x32_bf16(a, bw0, acc[rt][0], 0, 0, 0);
        acc[rt][1] = __builtin_amdgcn_mfma_f32_16x16x32_bf16(a, bw1, acc[rt][1], 0, 0, 0);
      }
    }

    // --- phase-1 epilogue: gelu -> hid (LDS, r5 scatter form)
#pragma unroll
    for (int rt = 0; rt < 4; ++rt)
#pragma unroll
      for (int i = 0; i < 2; ++i) {
        const int col = (2 * w + i) * 16 + l15;
#pragma unroll
        for (int r4 = 0; r4 < 4; ++r4) {
          const int row = rt * 16 + q * 4 + r4;
          hid[row * 136 + col] = f2bf(gelu(acc[rt][i][r4]));
        }
      }
    asm volatile("s_waitcnt lgkmcnt(0)" ::: "memory");
    __builtin_amdgcn_s_barrier();

    // --- phase 2: out = hid @ W2 + b2   [64 x 64] -> easm (bf16)
    {
      f32x4 acc2[4];
#pragma unroll
      for (int rt = 0; rt < 4; ++rt) acc2[rt] = (f32x4){bb2, bb2, bb2, bb2};
#pragma unroll
      for (int kc = 0; kc < 4; ++kc) {
        bf16x8 bw = *(const bf16x8*)&w2p[(size_t)((kc * 4 + w) * 64 + lane) * 8];
#pragma unroll
        for (int rt = 0; rt < 4; ++rt) {
          bf16x8 a = *(const bf16x8*)&hid[(rt * 16 + l15) * 136 + kc * 32 + q * 8];
          acc2[rt] = __builtin_amdgcn_mfma_f32_16x16x32_bf16(a, bw, acc2[rt], 0, 0, 0);
        }
      }
#pragma unroll
      for (int rt = 0; rt < 4; ++rt) {
        const int col = w * 16 + l15;
#pragma unroll
        for (int r4 = 0; r4 < 4; ++r4) {
          const int row = rt * 16 + q * 4 + r4;
          easm[row * 72 + col] = f2bf(acc2[rt][r4]);
        }
      }
    }
    asm volatile("s_waitcnt lgkmcnt(0)" ::: "memory");
    __builtin_amdgcn_s_barrier();
    // --- coalesced e_out write: 512 x uint4 = 64 rows x 128B
#pragma unroll
    for (int part = 0; part < 2; ++part) {
      const int idx = part * 256 + tid;
      const int r = idx >> 3, c = (idx & 7) * 8;
      ((uint4*)&ebuf[(size_t)ebase * 64])[idx] = *(const uint4*)&easm[r * 72 + c];
    }
  }
}

// ---- MFMA node MLP + skip + LayerNorm (r5 form).
__launch_bounds__(256)
__global__ void node_mfma(float* __restrict__ h, u16* __restrict__ hbf,
                          const u16* __restrict__ recvbf,
                          const u16* __restrict__ gpad,
                          const u16* __restrict__ w1p, const float* __restrict__ b1,
                          const u16* __restrict__ w2p, const float* __restrict__ b2,
                          const float* __restrict__ lns, const float* __restrict__ lnb) {
  __shared__ __align__(16) u16 hid[32 * 136];
  __shared__ __align__(16) float outs[32 * 68];

  const int tid = threadIdx.x;
  const int lane = tid & 63;
  const int w = tid >> 6;
  const int l15 = lane & 15;
  const int q = lane >> 4;
  const int mr = w & 1;
  const int ntb1 = (w >> 1) * 4;
  const int ntb2 = (w >> 1) * 2;
  const int arow = mr * 16 + l15;

  float bb1[4], bb2[2];
#pragma unroll
  for (int i = 0; i < 4; ++i) bb1[i] = b1[(ntb1 + i) * 16 + l15];
#pragma unroll
  for (int i = 0; i < 2; ++i) bb2[i] = b2[(ntb2 + i) * 16 + l15];

  const int nrow = tid >> 3;
  const int jc = (tid & 7) * 8;
  float sc8[8], bi8[8];
#pragma unroll
  for (int k = 0; k < 8; ++k) { sc8[k] = lns[jc + k]; bi8[k] = lnb[jc + k]; }

  const int NT = (NN + 31) / 32;
  for (int tile = blockIdx.x; tile < NT; tile += gridDim.x) {
    const int nbase = tile * 32;
    const int na = min(nbase + arow, NN - 1) * 64;   // clamped A-row offset

    // --- phase 1
    {
      f32x4 acc[4];
#pragma unroll
      for (int i = 0; i < 4; ++i) acc[i] = (f32x4){bb1[i], bb1[i], bb1[i], bb1[i]};
#pragma unroll
      for (int kc = 0; kc < 5; ++kc) {
        bf16x8 a;
        if (kc < 2) {
          a = *(const bf16x8*)&hbf[na + kc * 32 + q * 8];
        } else if (kc < 4) {
          a = *(const bf16x8*)&recvbf[na + (kc - 2) * 32 + q * 8];
        } else {
          a = *(const bf16x8*)&gpad[q * 8];
        }
#pragma unroll
        for (int i = 0; i < 4; ++i) {
          bf16x8 b = *(const bf16x8*)&w1p[(size_t)((kc * 8 + ntb1 + i) * 64 + lane) * 8];
          acc[i] = __builtin_amdgcn_mfma_f32_16x16x32_bf16(a, b, acc[i], 0, 0, 0);
        }
      }
#pragma unroll
      for (int i = 0; i < 4; ++i) {
        const int col = (ntb1 + i) * 16 + l15;
#pragma unroll
        for (int r4 = 0; r4 < 4; ++r4) {
          const int row = mr * 16 + q * 4 + r4;
          hid[row * 136 + col] = f2bf(gelu(acc[i][r4]));
        }
      }
    }
    __syncthreads();
    // --- phase 2: upd = hid @ W2 + b2 -> outs (fp32 LDS)
    {
      f32x4 acc[2];
#pragma unroll
      for (int i = 0; i < 2; ++i) acc[i] = (f32x4){bb2[i], bb2[i], bb2[i], bb2[i]};
#pragma unroll
      for (int kc = 0; kc < 4; ++kc) {
        bf16x8 a = *(const bf16x8*)&hid[arow * 136 + kc * 32 + q * 8];
#pragma unroll
        for (int i = 0; i < 2; ++i) {
          bf16x8 b = *(const bf16x8*)&w2p[(size_t)((kc * 4 + ntb2 + i) * 64 + lane) * 8];
          acc[i] = __builtin_amdgcn_mfma_f32_16x16x32_bf16(a, b, acc[i], 0, 0, 0);
        }
      }
#pragma unroll
      for (int i = 0; i < 2; ++i) {
        const int col = (ntb2 + i) * 16 + l15;
#pragma unroll
        for (int r4 = 0; r4 < 4; ++r4) {
          const int row = mr * 16 + q * 4 + r4;
          outs[row * 68 + col] = acc[i][r4];
        }
      }
    }
    __syncthreads();
    // --- skip + LayerNorm: 8 threads per node row, 8 cols each
    {
      const int n = nbase + nrow;
      if (n < NN) {
        float x[8];
        float4 hv0 = *(const float4*)&h[n * 64 + jc];
        float4 hv1 = *(const float4*)&h[n * 64 + jc + 4];
        x[0] = hv0.x + outs[nrow * 68 + jc + 0];
        x[1] = hv0.y + outs[nrow * 68 + jc + 1];
        x[2] = hv0.z + outs[nrow * 68 + jc + 2];
        x[3] = hv0.w + outs[nrow * 68 + jc + 3];
        x[4] = hv1.x + outs[nrow * 68 + jc + 4];
        x[5] = hv1.y + outs[nrow * 68 + jc + 5];
        x[6] = hv1.z + outs[nrow * 68 + jc + 6];
        x[7] = hv1.w + outs[nrow * 68 + jc + 7];
        float s = 0.f, qq = 0.f;
#pragma unroll
        for (int k = 0; k < 8; ++k) { s += x[k]; qq += x[k] * x[k]; }
#pragma unroll
        for (int off = 1; off < 8; off <<= 1) {
          s += __shfl_xor(s, off);
          qq += __shfl_xor(qq, off);
        }
        float mean = s * (1.0f / 64.0f);
        float var = fmaxf(qq * (1.0f / 64.0f) - mean * mean, 0.0f);
        float rstd = rsqrtf(var + 1e-6f);
        float o[8];
        ushort4 ob0, ob1;
#pragma unroll
        for (int k = 0; k < 8; ++k) o[k] = (x[k] - mean) * rstd * sc8[k] + bi8[k];
        *(float4*)&h[n * 64 + jc]     = make_float4(o[0], o[1], o[2], o[3]);
        *(float4*)&h[n * 64 + jc + 4] = make_float4(o[4], o[5], o[6], o[7]);
        ob0.x = f2bf(o[0]); ob0.y = f2bf(o[1]); ob0.z = f2bf(o[2]); ob0.w = f2bf(o[3]);
        ob1.x = f2bf(o[4]); ob1.y = f2bf(o[5]); ob1.z = f2bf(o[6]); ob1.w = f2bf(o[7]);
        *(ushort4*)&hbf[n * 64 + jc]     = ob0;
        *(ushort4*)&hbf[n * 64 + jc + 4] = ob1;
      }
    }
    __syncthreads();   // protect hid/outs reuse next tile
  }
}

// Output dtype: float32 (reference returns fp32).
__global__ void decode_kernel(const float* __restrict__ h, const float* __restrict__ w,
                              const float* __restrict__ b, float* __restrict__ out) {
  int gid = blockIdx.x * blockDim.x + threadIdx.x;
  if (gid >= NN * INF) return;
  int n = gid / 7, f = gid % 7;
  float acc = b[f];
#pragma unroll
  for (int k = 0; k < LAT; ++k)
    acc = fmaf(h[n * 64 + k], w[k * 7 + f], acc);
  out[gid] = acc;
}

extern "C" void kernel_launch(void* const* d_in, const int* in_sizes, int n_in,
                              void* d_out, int out_size, void* d_ws, size_t ws_size,
                              hipStream_t stream) {
  const float* nodes = (const float*)d_in[0];
  const int* senders = (const int*)d_in[1];
  const int* recvrs  = (const int*)d_in[2];
  const float* g     = (const float*)d_in[3];
  const float* emb_w = (const float*)d_in[4];
  const float* emb_b = (const float*)d_in[5];
  const float* ew1f  = (const float*)d_in[6];
  const float* ew1r  = (const float*)d_in[7];
  const float* eb1   = (const float*)d_in[8];
  const float* ew2   = (const float*)d_in[9];
  const float* eb2   = (const float*)d_in[10];
  const float* nw1   = (const float*)d_in[11];
  const float* nb1   = (const float*)d_in[12];
  const float* nw2   = (const float*)d_in[13];
  const float* nb2   = (const float*)d_in[14];
  const float* lns   = (const float*)d_in[15];
  const float* lnb   = (const float*)d_in[16];
  const float* dw    = (const float*)d_in[17];
  const float* db    = (const float*)d_in[18];

  char* cur = (char*)d_ws;
  float* h      = (float*)cur;  cur += (size_t)NN * LAT * 4;        // 12.8 MB
  u16*   ebuf   = (u16*)cur;    cur += (size_t)NE * LAT * 2;        // 102.4 MB
  u16*   hbf    = (u16*)cur;    cur += (size_t)NN * LAT * 2;        // 6.4 MB
  u16*   recvbf = (u16*)cur;    cur += (size_t)NN * LAT * 2;        // 6.4 MB
  u16*   ew1p[3]; for (int t = 0; t < 3; ++t) { ew1p[t] = (u16*)cur; cur += 7 * 8 * 64 * 8 * 2; }
  u16*   ew2p[3]; for (int t = 0; t < 3; ++t) { ew2p[t] = (u16*)cur; cur += 4 * 4 * 64 * 8 * 2; }
  u16*   nw1p[3]; for (int t = 0; t < 3; ++t) { nw1p[t] = (u16*)cur; cur += 5 * 8 * 64 * 8 * 2; }
  u16*   nw2p[3]; for (int t = 0; t < 3; ++t) { nw2p[t] = (u16*)cur; cur += 4 * 4 * 64 * 8 * 2; }
  u16*   gpad   = (u16*)cur;    cur += 256;
  int*   cnt    = (int*)cur;    cur += ((size_t)NN * 4 + 255) & ~(size_t)255;
  int*   cursor = (int*)cur;    cur += ((size_t)NN * 4 + 255) & ~(size_t)255;
  int*   rowptr = (int*)cur;    cur += ((size_t)(NN + 1) * 4 + 255) & ~(size_t)255;
  int*   ssnd   = (int*)cur;    cur += (size_t)NE * 4;              // 3.2 MB
  int*   srcv   = (int*)cur;    cur += (size_t)NE * 4;              // 3.2 MB

  // one-time receiver counting sort (graph fixed across steps)
  hipMemsetAsync(cnt, 0, (size_t)NN * 4, stream);
  hist_kernel<<<(NE + 255) / 256, 256, 0, stream>>>(recvrs, cnt);
  scan_kernel<<<1, 1024, 0, stream>>>(cnt, rowptr, cursor);
  scatter_kernel<<<(NE + 255) / 256, 256, 0, stream>>>(senders, recvrs, cursor, ssnd, srcv);

  // single consolidated pre-pack dispatch (13 jobs)
  PackJobs J;
  J.src[0] = ew1f;                       J.dst[0] = ew1p[0]; J.K[0] = 144; J.N[0] = 128; J.KC[0] = 5;
  J.src[1] = ew1r;                       J.dst[1] = ew1p[1]; J.K[1] = 208; J.N[1] = 128; J.KC[1] = 7;
  J.src[2] = ew1r + (size_t)208 * 128;   J.dst[2] = ew1p[2]; J.K[2] = 208; J.N[2] = 128; J.KC[2] = 7;
  for (int t = 0; t < 3; ++t) {
    J.src[3 + t] = ew2 + (size_t)t * 128 * 64;  J.dst[3 + t] = ew2p[t]; J.K[3 + t] = 128; J.N[3 + t] = 64; J.KC[3 + t] = 4;
    J.src[6 + t] = nw1 + (size_t)t * 144 * 128; J.dst[6 + t] = nw1p[t]; J.K[6 + t] = 144; J.N[6 + t] = 128; J.KC[6 + t] = 5;
    J.src[9 + t] = nw2 + (size_t)t * 128 * 64;  J.dst[9 + t] = nw2p[t]; J.K[9 + t] = 128; J.N[9 + t] = 64; J.KC[9 + t] = 4;
  }
  J.src[12] = g; J.dst[12] = gpad; J.K[12] = 0; J.N[12] = 0; J.KC[12] = 0;
  pack_all<<<dim3(16, 13), 256, 0, stream>>>(J);

  embed_kernel<<<(NN * LAT + 255) / 256, 256, 0, stream>>>(nodes, emb_w, emb_b, h, hbf);

  for (int t = 0; t < 3; ++t) {
    if (t == 0)
      edge_mfma<5, true><<<2084, 256, 0, stream>>>(hbf, ebuf,
          ssnd, srcv, gpad, ew1p[0], eb1, ew2p[0], eb2);
    else
      edge_mfma<7, false><<<2084, 256, 0, stream>>>(hbf, ebuf,
          ssnd, srcv, gpad, ew1p[t], eb1 + t * 128, ew2p[t], eb2 + t * 64);
    agg_kernel<<<(NN * 64 + 255) / 256, 256, 0, stream>>>(ebuf, rowptr, recvbf);
    node_mfma<<<1563, 256, 0, stream>>>(h, hbf, recvbf, gpad,
        nw1p[t], nb1 + t * 128, nw2p[t], nb2 + t * 64,
        lns + t * 64, lnb + t * 64);
  }

  decode_kernel<<<(NN * INF + 255) / 256, 256, 0, stream>>>(h, dw, db, (float*)d_out);
}

// Round 10
// 713.131 us; speedup vs baseline: 1.1268x; 1.0710x over previous
//
#include <hip/hip_runtime.h>

#define NN 50000
#define NE 800000
#define INF 7
#define GD 16
#define LAT 64
#define HID 128

typedef unsigned short u16;
typedef __attribute__((ext_vector_type(8))) __bf16 bf16x8;
typedef __attribute__((ext_vector_type(4))) float f32x4;

__device__ __forceinline__ float bf2f(u16 u) {
  union { unsigned int i; float f; } v; v.i = ((unsigned int)u) << 16; return v.f;
}
__device__ __forceinline__ float blo(unsigned int u) {
  union { unsigned int i; float f; } v; v.i = u << 16; return v.f;
}
__device__ __forceinline__ float bhi(unsigned int u) {
  union { unsigned int i; float f; } v; v.i = u & 0xffff0000u; return v.f;
}
__device__ __forceinline__ u16 f2bf(float f) {
  union { float f; unsigned int i; } v; v.f = f;
  unsigned int x = v.i;
  return (u16)((x + 0x7fffu + ((x >> 16) & 1u)) >> 16);
}
// jax.nn.gelu approximate (tanh form) as x*sigmoid(2z) with v_rcp (r11-verified).
__device__ __forceinline__ float gelu(float x) {
  float u = x * x;
  float p = fmaf(0.044715f * u, x, x);
  float e = __expf(-1.5957691216057308f * p);
  return x * __builtin_amdgcn_rcpf(e + 1.0f);
}

// ---- consolidated weight pre-pack: 13 jobs in one dispatch.
struct PackJobs {
  const float* src[13];
  u16* dst[13];
  int K[13];
  int N[13];
  int KC[13];
};

__global__ void pack_all(PackJobs J) {
  const int j = blockIdx.y;
  const int KC = J.KC[j];
  const float* W = J.src[j];
  u16* out = J.dst[j];
  int t = blockIdx.x * blockDim.x + threadIdx.x;
  if (KC == 0) {            // gpad job
    if (t < 32) out[t] = (t < GD) ? f2bf(W[t]) : (u16)0;
    return;
  }
  const int K = J.K[j], N = J.N[j];
  const int NT = N >> 4;
  if (t >= KC * NT * 64) return;
  int l = t & 63;
  int nt = (t >> 6) % NT;
  int kc = t / (64 * NT);
  int n = nt * 16 + (l & 15);
  int kbase = kc * 32 + (l >> 4) * 8;
  ushort4 lo, hi;
  u16 v[8];
#pragma unroll
  for (int jj = 0; jj < 8; ++jj) {
    int k = kbase + jj;
    v[jj] = (k < K) ? f2bf(W[k * N + n]) : (u16)0;
  }
  lo.x = v[0]; lo.y = v[1]; lo.z = v[2]; lo.w = v[3];
  hi.x = v[4]; hi.y = v[5]; hi.z = v[6]; hi.w = v[7];
  ushort4* dst = (ushort4*)&out[(size_t)t * 8];
  dst[0] = lo; dst[1] = hi;
}

// ---- counting sort of edges by receiver (graph fixed across all 3 steps).
__global__ void hist_kernel(const int* __restrict__ rcv, int* __restrict__ cnt) {
  int i = blockIdx.x * blockDim.x + threadIdx.x;
  if (i < NE) atomicAdd(&cnt[rcv[i]], 1);
}

// Chunked COALESCED block scan (r5).
__launch_bounds__(1024)
__global__ void scan_kernel(const int* __restrict__ cnt, int* __restrict__ rowptr,
                            int* __restrict__ cursor) {
  __shared__ int wsum[16];
  const int t = threadIdx.x;
  const int lane = t & 63;
  const int wid = t >> 6;
  int carry = 0;
  for (int base = 0; base < NN; base += 1024) {
    const int i = base + t;
    int v = (i < NN) ? cnt[i] : 0;
    int x = v;
#pragma unroll
    for (int off = 1; off < 64; off <<= 1) {
      int y = __shfl_up(x, off);
      if (lane >= off) x += y;
    }
    if (lane == 63) wsum[wid] = x;
    __syncthreads();
    if (wid == 0 && lane < 16) {
      int s = wsum[lane];
#pragma unroll
      for (int off = 1; off < 16; off <<= 1) {
        int y = __shfl_up(s, off);
        if (lane >= off) s += y;
      }
      wsum[lane] = s;   // inclusive wave prefix
    }
    __syncthreads();
    const int excl = carry + (wid > 0 ? wsum[wid - 1] : 0) + (x - v);
    if (i < NN) { rowptr[i] = excl; cursor[i] = excl; }
    carry += wsum[15];  // chunk total (uniform across block)
    __syncthreads();    // protect wsum reuse next chunk
  }
  if (t == 0) rowptr[NN] = NE;
}

__global__ void scatter_kernel(const int* __restrict__ snd, const int* __restrict__ rcv,
                               int* __restrict__ cursor, int* __restrict__ ssnd,
                               int* __restrict__ srcv) {
  int i = blockIdx.x * blockDim.x + threadIdx.x;
  if (i >= NE) return;
  int r = rcv[i];
  int p = atomicAdd(&cursor[r], 1);
  ssnd[p] = snd[i];
  srcv[p] = r;
}

__global__ void embed_kernel(const float* __restrict__ nodes, const float* __restrict__ w,
                             const float* __restrict__ b, float* __restrict__ h,
                             u16* __restrict__ hbf) {
  int gid = blockIdx.x * blockDim.x + threadIdx.x;
  if (gid >= NN * LAT) return;
  int n = gid >> 6, j = gid & 63;
  float acc = b[j];
#pragma unroll
  for (int k = 0; k < INF; ++k)
    acc = fmaf(nodes[n * INF + k], w[k * LAT + j], acc);
  h[gid] = acc;
  hbf[gid] = f2bf(acc);
}

// ---- wave-per-node CSR segment-sum over receiver-sorted ebuf (r5).
__launch_bounds__(256)
__global__ void agg_kernel(const u16* __restrict__ ebuf, const int* __restrict__ rowptr,
                           u16* __restrict__ recvbf) {
  const int gid = blockIdx.x * blockDim.x + threadIdx.x;
  const int node = gid >> 6;
  if (node >= NN) return;
  const int lane = threadIdx.x & 63;
  const int sub = lane >> 3;
  const int c8 = (lane & 7) * 8;
  const int e0 = rowptr[node], e1 = rowptr[node + 1];
  float a[8] = {0.f, 0.f, 0.f, 0.f, 0.f, 0.f, 0.f, 0.f};
  for (int e = e0 + sub; e < e1; e += 8) {
    uint4 v = *(const uint4*)&ebuf[(size_t)e * 64 + c8];
    a[0] += blo(v.x); a[1] += bhi(v.x);
    a[2] += blo(v.y); a[3] += bhi(v.y);
    a[4] += blo(v.z); a[5] += bhi(v.z);
    a[6] += blo(v.w); a[7] += bhi(v.w);
  }
#pragma unroll
  for (int k = 0; k < 8; ++k) {
    a[k] += __shfl_xor(a[k], 8);
    a[k] += __shfl_xor(a[k], 16);
    a[k] += __shfl_xor(a[k], 32);
  }
  if (sub == 0) {
    ushort4 p0, p1;
    p0.x = f2bf(a[0]); p0.y = f2bf(a[1]); p0.z = f2bf(a[2]); p0.w = f2bf(a[3]);
    p1.x = f2bf(a[4]); p1.y = f2bf(a[5]); p1.z = f2bf(a[6]); p1.w = f2bf(a[7]);
    *(ushort4*)&recvbf[(size_t)node * 64 + c8]     = p0;
    *(ushort4*)&recvbf[(size_t)node * 64 + c8 + 4] = p1;
  }
}

// ---- MFMA edge MLP. r10: exact r5 structure (M=32, 4 waves, acur prefetch,
// no-vmcnt-drain barriers) + W1 STAGED IN LDS once per block. Phase-1 weight
// reads were the per-tile global stall (36KB/wave issued -> ~3.6GB/dispatch
// ~= L2 ceiling ~= the measured 103us). Staged kc<KCS (KCS=min(KC,6), 64KB
// static-LDS limit) -> phase 1 has ZERO global loads; kc=6 (KC=7) + W2 stay
// global. M=64 quarantined (r8 spill, r9 latency-serialization).
// K layout FIRST: [s 64][r 64][g 16|pad] = 160 (KC=5, AF=4)
//          else : [e 64][s 64][r 64][g 16|pad] = 224 (KC=7, AF=6)
template <int KC, bool FIRST>
__launch_bounds__(256, 2)
__global__ void edge_mfma(const u16* __restrict__ hbf, u16* __restrict__ ebuf,
                          const int* __restrict__ snd, const int* __restrict__ rcv,
                          const u16* __restrict__ gpad,
                          const u16* __restrict__ w1p, const float* __restrict__ b1,
                          const u16* __restrict__ w2p, const float* __restrict__ b2) {
  constexpr int KCS = (KC < 6) ? KC : 6;            // staged kc count
  __shared__ __align__(16) u16 w1lds[KCS * 8 * 64 * 8];
  __shared__ __align__(16) u16 hid[32 * 136];
  __shared__ __align__(16) u16 easm[32 * 64];

  const int tid = threadIdx.x;
  const int lane = tid & 63;
  const int w = tid >> 6;
  const int l15 = lane & 15;
  const int q = lane >> 4;
  const int mr = w & 1;              // row-tile (16 rows) for both phases
  const int ntb1 = (w >> 1) * 4;     // phase-1 col-tiles (4 of 8)
  const int ntb2 = (w >> 1) * 2;     // phase-2 col-tiles (2 of 4)
  const int arow = mr * 16 + l15;
  const int NTILE = NE / 32;
  constexpr int AF = FIRST ? 4 : 6;  // per-tile A fragments (g is loop-invariant)

  // ---- cooperative W1 stage: KCS*512 uint4 (16B) coalesced copies
  {
    const int n4 = KCS * 512;
    for (int i = tid; i < n4; i += 256)
      ((uint4*)w1lds)[i] = ((const uint4*)w1p)[i];
  }

  float bb1[4], bb2[2];
#pragma unroll
  for (int i = 0; i < 4; ++i) bb1[i] = b1[(ntb1 + i) * 16 + l15];
#pragma unroll
  for (int i = 0; i < 2; ++i) bb2[i] = b2[(ntb2 + i) * 16 + l15];
  const bf16x8 gfrag = *(const bf16x8*)&gpad[q * 8];

  // ---- A pipeline: acur holds tile t's fragments; s_cur/r_cur hold t+1's idx
  bf16x8 acur[AF];
  int s_cur = 0, r_cur = 0;
  {
    const int t0 = blockIdx.x;
    if (t0 < NTILE) {
      const int eg0 = t0 * 32 + arow;
      const int s0 = snd[eg0], r0 = rcv[eg0];
      if (!FIRST) {
#pragma unroll
        for (int kc = 0; kc < 2; ++kc)
          acur[kc] = *(const bf16x8*)&ebuf[(size_t)eg0 * 64 + kc * 32 + q * 8];
      }
#pragma unroll
      for (int kc = 0; kc < 2; ++kc)
        acur[(FIRST ? 0 : 2) + kc] = *(const bf16x8*)&hbf[s0 * 64 + kc * 32 + q * 8];
#pragma unroll
      for (int kc = 0; kc < 2; ++kc)
        acur[(FIRST ? 2 : 4) + kc] = *(const bf16x8*)&hbf[r0 * 64 + kc * 32 + q * 8];
      const int t1 = t0 + gridDim.x;
      if (t1 < NTILE) {
        s_cur = snd[t1 * 32 + arow];
        r_cur = rcv[t1 * 32 + arow];
      }
    }
  }
  __syncthreads();   // W1 stage visible to all waves

  for (int tile = blockIdx.x; tile < NTILE; tile += gridDim.x) {
    const int ebase = tile * 32;

    // --- phase 1: hid = gelu(in @ W1 + b1)  [32 x 128]
    // A from registers (prefetched), W1 from LDS -> NO global loads in phase 1
    f32x4 acc[4];
#pragma unroll
    for (int i = 0; i < 4; ++i) acc[i] = (f32x4){bb1[i], bb1[i], bb1[i], bb1[i]};
#pragma unroll
    for (int kc = 0; kc < KC; ++kc) {
      bf16x8 a = (kc < AF) ? acur[kc] : gfrag;
#pragma unroll
      for (int i = 0; i < 4; ++i) {
        bf16x8 b = (kc < KCS)
          ? *(const bf16x8*)&w1lds[(size_t)((kc * 8 + ntb1 + i) * 64 + lane) * 8]
          : *(const bf16x8*)&w1p  [(size_t)((kc * 8 + ntb1 + i) * 64 + lane) * 8];
        acc[i] = __builtin_amdgcn_mfma_f32_16x16x32_bf16(a, b, acc[i], 0, 0, 0);
      }
    }

    // --- prefetch next tile's A rows (reuses acur; lands during phase2+store)
    {
      const int tn = tile + gridDim.x;
      if (tn < NTILE) {
        const int egn = tn * 32 + arow;
        const int soffn = s_cur * 64;
        const int roffn = r_cur * 64;
        if (!FIRST) {
#pragma unroll
          for (int kc = 0; kc < 2; ++kc)
            acur[kc] = *(const bf16x8*)&ebuf[(size_t)egn * 64 + kc * 32 + q * 8];
        }
#pragma unroll
        for (int kc = 0; kc < 2; ++kc)
          acur[(FIRST ? 0 : 2) + kc] = *(const bf16x8*)&hbf[soffn + kc * 32 + q * 8];
#pragma unroll
        for (int kc = 0; kc < 2; ++kc)
          acur[(FIRST ? 2 : 4) + kc] = *(const bf16x8*)&hbf[roffn + kc * 32 + q * 8];
        const int tn2 = tn + gridDim.x;
        if (tn2 < NTILE) {
          s_cur = snd[tn2 * 32 + arow];
          r_cur = rcv[tn2 * 32 + arow];
        }
      }
    }

    // --- phase-1 epilogue: gelu -> hid (LDS)
#pragma unroll
    for (int i = 0; i < 4; ++i) {
      const int col = (ntb1 + i) * 16 + l15;
#pragma unroll
      for (int r4 = 0; r4 < 4; ++r4) {
        const int row = mr * 16 + q * 4 + r4;
        hid[row * 136 + col] = f2bf(gelu(acc[i][r4]));
      }
    }
    // barrier WITHOUT vmcnt drain (prefetch stays in flight)
    asm volatile("s_waitcnt lgkmcnt(0)" ::: "memory");
    __builtin_amdgcn_s_barrier();

    // --- phase 2: out = hid @ W2 + b2   [32 x 64] -> easm (bf16)
    {
      f32x4 acc2[2];
#pragma unroll
      for (int i = 0; i < 2; ++i) acc2[i] = (f32x4){bb2[i], bb2[i], bb2[i], bb2[i]};
#pragma unroll
      for (int kc = 0; kc < 4; ++kc) {
        bf16x8 a = *(const bf16x8*)&hid[arow * 136 + kc * 32 + q * 8];
#pragma unroll
        for (int i = 0; i < 2; ++i) {
          bf16x8 b = *(const bf16x8*)&w2p[(size_t)((kc * 4 + ntb2 + i) * 64 + lane) * 8];
          acc2[i] = __builtin_amdgcn_mfma_f32_16x16x32_bf16(a, b, acc2[i], 0, 0, 0);
        }
      }
#pragma unroll
      for (int i = 0; i < 2; ++i) {
        const int col = (ntb2 + i) * 16 + l15;
#pragma unroll
        for (int r4 = 0; r4 < 4; ++r4) {
          const int row = mr * 16 + q * 4 + r4;
          easm[row * 64 + col] = f2bf(acc2[i][r4]);
        }
      }
    }
    asm volatile("s_waitcnt lgkmcnt(0)" ::: "memory");
    __builtin_amdgcn_s_barrier();
    // --- coalesced e_out write: 256 threads x 16B = 32 rows x 128B
    ((uint4*)&ebuf[(size_t)ebase * 64])[tid] = ((const uint4*)easm)[tid];
  }
}

// ---- MFMA node MLP + skip + LayerNorm (r5 form; one tile per block, no
// weight re-reads -> no staging here).
__launch_bounds__(256)
__global__ void node_mfma(float* __restrict__ h, u16* __restrict__ hbf,
                          const u16* __restrict__ recvbf,
                          const u16* __restrict__ gpad,
                          const u16* __restrict__ w1p, const float* __restrict__ b1,
                          const u16* __restrict__ w2p, const float* __restrict__ b2,
                          const float* __restrict__ lns, const float* __restrict__ lnb) {
  __shared__ __align__(16) u16 hid[32 * 136];
  __shared__ __align__(16) float outs[32 * 68];

  const int tid = threadIdx.x;
  const int lane = tid & 63;
  const int w = tid >> 6;
  const int l15 = lane & 15;
  const int q = lane >> 4;
  const int mr = w & 1;
  const int ntb1 = (w >> 1) * 4;
  const int ntb2 = (w >> 1) * 2;
  const int arow = mr * 16 + l15;

  float bb1[4], bb2[2];
#pragma unroll
  for (int i = 0; i < 4; ++i) bb1[i] = b1[(ntb1 + i) * 16 + l15];
#pragma unroll
  for (int i = 0; i < 2; ++i) bb2[i] = b2[(ntb2 + i) * 16 + l15];

  const int nrow = tid >> 3;
  const int jc = (tid & 7) * 8;
  float sc8[8], bi8[8];
#pragma unroll
  for (int k = 0; k < 8; ++k) { sc8[k] = lns[jc + k]; bi8[k] = lnb[jc + k]; }

  const int NT = (NN + 31) / 32;
  for (int tile = blockIdx.x; tile < NT; tile += gridDim.x) {
    const int nbase = tile * 32;
    const int na = min(nbase + arow, NN - 1) * 64;   // clamped A-row offset

    // --- phase 1
    {
      f32x4 acc[4];
#pragma unroll
      for (int i = 0; i < 4; ++i) acc[i] = (f32x4){bb1[i], bb1[i], bb1[i], bb1[i]};
#pragma unroll
      for (int kc = 0; kc < 5; ++kc) {
        bf16x8 a;
        if (kc < 2) {
          a = *(const bf16x8*)&hbf[na + kc * 32 + q * 8];
        } else if (kc < 4) {
          a = *(const bf16x8*)&recvbf[na + (kc - 2) * 32 + q * 8];
        } else {
          a = *(const bf16x8*)&gpad[q * 8];
        }
#pragma unroll
        for (int i = 0; i < 4; ++i) {
          bf16x8 b = *(const bf16x8*)&w1p[(size_t)((kc * 8 + ntb1 + i) * 64 + lane) * 8];
          acc[i] = __builtin_amdgcn_mfma_f32_16x16x32_bf16(a, b, acc[i], 0, 0, 0);
        }
      }
#pragma unroll
      for (int i = 0; i < 4; ++i) {
        const int col = (ntb1 + i) * 16 + l15;
#pragma unroll
        for (int r4 = 0; r4 < 4; ++r4) {
          const int row = mr * 16 + q * 4 + r4;
          hid[row * 136 + col] = f2bf(gelu(acc[i][r4]));
        }
      }
    }
    __syncthreads();
    // --- phase 2: upd = hid @ W2 + b2 -> outs (fp32 LDS)
    {
      f32x4 acc[2];
#pragma unroll
      for (int i = 0; i < 2; ++i) acc[i] = (f32x4){bb2[i], bb2[i], bb2[i], bb2[i]};
#pragma unroll
      for (int kc = 0; kc < 4; ++kc) {
        bf16x8 a = *(const bf16x8*)&hid[arow * 136 + kc * 32 + q * 8];
#pragma unroll
        for (int i = 0; i < 2; ++i) {
          bf16x8 b = *(const bf16x8*)&w2p[(size_t)((kc * 4 + ntb2 + i) * 64 + lane) * 8];
          acc[i] = __builtin_amdgcn_mfma_f32_16x16x32_bf16(a, b, acc[i], 0, 0, 0);
        }
      }
#pragma unroll
      for (int i = 0; i < 2; ++i) {
        const int col = (ntb2 + i) * 16 + l15;
#pragma unroll
        for (int r4 = 0; r4 < 4; ++r4) {
          const int row = mr * 16 + q * 4 + r4;
          outs[row * 68 + col] = acc[i][r4];
        }
      }
    }
    __syncthreads();
    // --- skip + LayerNorm: 8 threads per node row, 8 cols each
    {
      const int n = nbase + nrow;
      if (n < NN) {
        float x[8];
        float4 hv0 = *(const float4*)&h[n * 64 + jc];
        float4 hv1 = *(const float4*)&h[n * 64 + jc + 4];
        x[0] = hv0.x + outs[nrow * 68 + jc + 0];
        x[1] = hv0.y + outs[nrow * 68 + jc + 1];
        x[2] = hv0.z + outs[nrow * 68 + jc + 2];
        x[3] = hv0.w + outs[nrow * 68 + jc + 3];
        x[4] = hv1.x + outs[nrow * 68 + jc + 4];
        x[5] = hv1.y + outs[nrow * 68 + jc + 5];
        x[6] = hv1.z + outs[nrow * 68 + jc + 6];
        x[7] = hv1.w + outs[nrow * 68 + jc + 7];
        float s = 0.f, qq = 0.f;
#pragma unroll
        for (int k = 0; k < 8; ++k) { s += x[k]; qq += x[k] * x[k]; }
#pragma unroll
        for (int off = 1; off < 8; off <<= 1) {
          s += __shfl_xor(s, off);
          qq += __shfl_xor(qq, off);
        }
        float mean = s * (1.0f / 64.0f);
        float var = fmaxf(qq * (1.0f / 64.0f) - mean * mean, 0.0f);
        float rstd = rsqrtf(var + 1e-6f);
        float o[8];
        ushort4 ob0, ob1;
#pragma unroll
        for (int k = 0; k < 8; ++k) o[k] = (x[k] - mean) * rstd * sc8[k] + bi8[k];
        *(float4*)&h[n * 64 + jc]     = make_float4(o[0], o[1], o[2], o[3]);
        *(float4*)&h[n * 64 + jc + 4] = make_float4(o[4], o[5], o[6], o[7]);
        ob0.x = f2bf(o[0]); ob0.y = f2bf(o[1]); ob0.z = f2bf(o[2]); ob0.w = f2bf(o[3]);
        ob1.x = f2bf(o[4]); ob1.y = f2bf(o[5]); ob1.z = f2bf(o[6]); ob1.w = f2bf(o[7]);
        *(ushort4*)&hbf[n * 64 + jc]     = ob0;
        *(ushort4*)&hbf[n * 64 + jc + 4] = ob1;
      }
    }
    __syncthreads();   // protect hid/outs reuse next tile
  }
}

// Output dtype: float32 (reference returns fp32).
__global__ void decode_kernel(const float* __restrict__ h, const float* __restrict__ w,
                              const float* __restrict__ b, float* __restrict__ out) {
  int gid = blockIdx.x * blockDim.x + threadIdx.x;
  if (gid >= NN * INF) return;
  int n = gid / 7, f = gid % 7;
  float acc = b[f];
#pragma unroll
  for (int k = 0; k < LAT; ++k)
    acc = fmaf(h[n * 64 + k], w[k * 7 + f], acc);
  out[gid] = acc;
}

extern "C" void kernel_launch(void* const* d_in, const int* in_sizes, int n_in,
                              void* d_out, int out_size, void* d_ws, size_t ws_size,
                              hipStream_t stream) {
  const float* nodes = (const float*)d_in[0];
  const int* senders = (const int*)d_in[1];
  const int* recvrs  = (const int*)d_in[2];
  const float* g     = (const float*)d_in[3];
  const float* emb_w = (const float*)d_in[4];
  const float* emb_b = (const float*)d_in[5];
  const float* ew1f  = (const float*)d_in[6];
  const float* ew1r  = (const float*)d_in[7];
  const float* eb1   = (const float*)d_in[8];
  const float* ew2   = (const float*)d_in[9];
  const float* eb2   = (const float*)d_in[10];
  const float* nw1   = (const float*)d_in[11];
  const float* nb1   = (const float*)d_in[12];
  const float* nw2   = (const float*)d_in[13];
  const float* nb2   = (const float*)d_in[14];
  const float* lns   = (const float*)d_in[15];
  const float* lnb   = (const float*)d_in[16];
  const float* dw    = (const float*)d_in[17];
  const float* db    = (const float*)d_in[18];

  char* cur = (char*)d_ws;
  float* h      = (float*)cur;  cur += (size_t)NN * LAT * 4;        // 12.8 MB
  u16*   ebuf   = (u16*)cur;    cur += (size_t)NE * LAT * 2;        // 102.4 MB
  u16*   hbf    = (u16*)cur;    cur += (size_t)NN * LAT * 2;        // 6.4 MB
  u16*   recvbf = (u16*)cur;    cur += (size_t)NN * LAT * 2;        // 6.4 MB
  u16*   ew1p[3]; for (int t = 0; t < 3; ++t) { ew1p[t] = (u16*)cur; cur += 7 * 8 * 64 * 8 * 2; }
  u16*   ew2p[3]; for (int t = 0; t < 3; ++t) { ew2p[t] = (u16*)cur; cur += 4 * 4 * 64 * 8 * 2; }
  u16*   nw1p[3]; for (int t = 0; t < 3; ++t) { nw1p[t] = (u16*)cur; cur += 5 * 8 * 64 * 8 * 2; }
  u16*   nw2p[3]; for (int t = 0; t < 3; ++t) { nw2p[t] = (u16*)cur; cur += 4 * 4 * 64 * 8 * 2; }
  u16*   gpad   = (u16*)cur;    cur += 256;
  int*   cnt    = (int*)cur;    cur += ((size_t)NN * 4 + 255) & ~(size_t)255;
  int*   cursor = (int*)cur;    cur += ((size_t)NN * 4 + 255) & ~(size_t)255;
  int*   rowptr = (int*)cur;    cur += ((size_t)(NN + 1) * 4 + 255) & ~(size_t)255;
  int*   ssnd   = (int*)cur;    cur += (size_t)NE * 4;              // 3.2 MB
  int*   srcv   = (int*)cur;    cur += (size_t)NE * 4;              // 3.2 MB

  // one-time receiver counting sort (graph fixed across steps)
  hipMemsetAsync(cnt, 0, (size_t)NN * 4, stream);
  hist_kernel<<<(NE + 255) / 256, 256, 0, stream>>>(recvrs, cnt);
  scan_kernel<<<1, 1024, 0, stream>>>(cnt, rowptr, cursor);
  scatter_kernel<<<(NE + 255) / 256, 256, 0, stream>>>(senders, recvrs, cursor, ssnd, srcv);

  // single consolidated pre-pack dispatch (13 jobs)
  PackJobs J;
  J.src[0] = ew1f;                       J.dst[0] = ew1p[0]; J.K[0] = 144; J.N[0] = 128; J.KC[0] = 5;
  J.src[1] = ew1r;                       J.dst[1] = ew1p[1]; J.K[1] = 208; J.N[1] = 128; J.KC[1] = 7;
  J.src[2] = ew1r + (size_t)208 * 128;   J.dst[2] = ew1p[2]; J.K[2] = 208; J.N[2] = 128; J.KC[2] = 7;
  for (int t = 0; t < 3; ++t) {
    J.src[3 + t] = ew2 + (size_t)t * 128 * 64;  J.dst[3 + t] = ew2p[t]; J.K[3 + t] = 128; J.N[3 + t] = 64; J.KC[3 + t] = 4;
    J.src[6 + t] = nw1 + (size_t)t * 144 * 128; J.dst[6 + t] = nw1p[t]; J.K[6 + t] = 144; J.N[6 + t] = 128; J.KC[6 + t] = 5;
    J.src[9 + t] = nw2 + (size_t)t * 128 * 64;  J.dst[9 + t] = nw2p[t]; J.K[9 + t] = 128; J.N[9 + t] = 64; J.KC[9 + t] = 4;
  }
  J.src[12] = g; J.dst[12] = gpad; J.K[12] = 0; J.N[12] = 0; J.KC[12] = 0;
  pack_all<<<dim3(16, 13), 256, 0, stream>>>(J);

  embed_kernel<<<(NN * LAT + 255) / 256, 256, 0, stream>>>(nodes, emb_w, emb_b, h, hbf);

  for (int t = 0; t < 3; ++t) {
    if (t == 0)
      edge_mfma<5, true><<<2048, 256, 0, stream>>>(hbf, ebuf,
          ssnd, srcv, gpad, ew1p[0], eb1, ew2p[0], eb2);
    else
      edge_mfma<7, false><<<2048, 256, 0, stream>>>(hbf, ebuf,
          ssnd, srcv, gpad, ew1p[t], eb1 + t * 128, ew2p[t], eb2 + t * 64);
    agg_kernel<<<(NN * 64 + 255) / 256, 256, 0, stream>>>(ebuf, rowptr, recvbf);
    node_mfma<<<1563, 256, 0, stream>>>(h, hbf, recvbf, gpad,
        nw1p[t], nb1 + t * 128, nw2p[t], nb2 + t * 64,
        lns + t * 64, lnb + t * 64);
  }

  decode_kernel<<<(NN * INF + 255) / 256, 256, 0, stream>>>(h, dw, db, (float*)d_out);
}

// Round 11
// 706.553 us; speedup vs baseline: 1.1373x; 1.0093x over previous
//
#include <hip/hip_runtime.h>

#define NN 50000
#define NE 800000
#define INF 7
#define GD 16
#define LAT 64
#define HID 128

typedef unsigned short u16;
typedef __attribute__((ext_vector_type(8))) __bf16 bf16x8;
typedef __attribute__((ext_vector_type(4))) float f32x4;

__device__ __forceinline__ float bf2f(u16 u) {
  union { unsigned int i; float f; } v; v.i = ((unsigned int)u) << 16; return v.f;
}
__device__ __forceinline__ float blo(unsigned int u) {
  union { unsigned int i; float f; } v; v.i = u << 16; return v.f;
}
__device__ __forceinline__ float bhi(unsigned int u) {
  union { unsigned int i; float f; } v; v.i = u & 0xffff0000u; return v.f;
}
__device__ __forceinline__ u16 f2bf(float f) {
  union { float f; unsigned int i; } v; v.f = f;
  unsigned int x = v.i;
  return (u16)((x + 0x7fffu + ((x >> 16) & 1u)) >> 16);
}
// jax.nn.gelu approximate (tanh form) as x*sigmoid(2z) with v_rcp (r11-verified).
__device__ __forceinline__ float gelu(float x) {
  float u = x * x;
  float p = fmaf(0.044715f * u, x, x);
  float e = __expf(-1.5957691216057308f * p);
  return x * __builtin_amdgcn_rcpf(e + 1.0f);
}

// ---- consolidated weight pre-pack: 13 jobs in one dispatch.
struct PackJobs {
  const float* src[13];
  u16* dst[13];
  int K[13];
  int N[13];
  int KC[13];
};

__global__ void pack_all(PackJobs J) {
  const int j = blockIdx.y;
  const int KC = J.KC[j];
  const float* W = J.src[j];
  u16* out = J.dst[j];
  int t = blockIdx.x * blockDim.x + threadIdx.x;
  if (KC == 0) {            // gpad job
    if (t < 32) out[t] = (t < GD) ? f2bf(W[t]) : (u16)0;
    return;
  }
  const int K = J.K[j], N = J.N[j];
  const int NT = N >> 4;
  if (t >= KC * NT * 64) return;
  int l = t & 63;
  int nt = (t >> 6) % NT;
  int kc = t / (64 * NT);
  int n = nt * 16 + (l & 15);
  int kbase = kc * 32 + (l >> 4) * 8;
  ushort4 lo, hi;
  u16 v[8];
#pragma unroll
  for (int jj = 0; jj < 8; ++jj) {
    int k = kbase + jj;
    v[jj] = (k < K) ? f2bf(W[k * N + n]) : (u16)0;
  }
  lo.x = v[0]; lo.y = v[1]; lo.z = v[2]; lo.w = v[3];
  hi.x = v[4]; hi.y = v[5]; hi.z = v[6]; hi.w = v[7];
  ushort4* dst = (ushort4*)&out[(size_t)t * 8];
  dst[0] = lo; dst[1] = hi;
}

// ---- counting sort of edges by receiver (graph fixed across all 3 steps;
// sorted once, amortized). Removes ALL recv atomics from the hot loop.
__global__ void hist_kernel(const int* __restrict__ rcv, int* __restrict__ cnt) {
  int i = blockIdx.x * blockDim.x + threadIdx.x;
  if (i < NE) atomicAdd(&cnt[rcv[i]], 1);
}

// Chunked COALESCED block scan (r5: coalesced chunks fixed the 112us cost).
__launch_bounds__(1024)
__global__ void scan_kernel(const int* __restrict__ cnt, int* __restrict__ rowptr,
                            int* __restrict__ cursor) {
  __shared__ int wsum[16];
  const int t = threadIdx.x;
  const int lane = t & 63;
  const int wid = t >> 6;
  int carry = 0;
  for (int base = 0; base < NN; base += 1024) {
    const int i = base + t;
    int v = (i < NN) ? cnt[i] : 0;
    int x = v;
#pragma unroll
    for (int off = 1; off < 64; off <<= 1) {
      int y = __shfl_up(x, off);
      if (lane >= off) x += y;
    }
    if (lane == 63) wsum[wid] = x;
    __syncthreads();
    if (wid == 0 && lane < 16) {
      int s = wsum[lane];
#pragma unroll
      for (int off = 1; off < 16; off <<= 1) {
        int y = __shfl_up(s, off);
        if (lane >= off) s += y;
      }
      wsum[lane] = s;   // inclusive wave prefix
    }
    __syncthreads();
    const int excl = carry + (wid > 0 ? wsum[wid - 1] : 0) + (x - v);
    if (i < NN) { rowptr[i] = excl; cursor[i] = excl; }
    carry += wsum[15];  // chunk total (uniform across block)
    __syncthreads();    // protect wsum reuse next chunk
  }
  if (t == 0) rowptr[NN] = NE;
}

__global__ void scatter_kernel(const int* __restrict__ snd, const int* __restrict__ rcv,
                               int* __restrict__ cursor, int* __restrict__ ssnd,
                               int* __restrict__ srcv) {
  int i = blockIdx.x * blockDim.x + threadIdx.x;
  if (i >= NE) return;
  int r = rcv[i];
  int p = atomicAdd(&cursor[r], 1);
  ssnd[p] = snd[i];
  srcv[p] = r;
}

__global__ void embed_kernel(const float* __restrict__ nodes, const float* __restrict__ w,
                             const float* __restrict__ b, float* __restrict__ h,
                             u16* __restrict__ hbf) {
  int gid = blockIdx.x * blockDim.x + threadIdx.x;
  if (gid >= NN * LAT) return;
  int n = gid >> 6, j = gid & 63;
  float acc = b[j];
#pragma unroll
  for (int k = 0; k < INF; ++k)
    acc = fmaf(nodes[n * INF + k], w[k * LAT + j], acc);
  h[gid] = acc;
  hbf[gid] = f2bf(acc);
}

// ---- wave-per-node CSR segment-sum over receiver-sorted ebuf.
// 8 edges in flight (sub = lane>>3), 8 bf16 cols per lane via uint4 (16B).
__launch_bounds__(256)
__global__ void agg_kernel(const u16* __restrict__ ebuf, const int* __restrict__ rowptr,
                           u16* __restrict__ recvbf) {
  const int gid = blockIdx.x * blockDim.x + threadIdx.x;
  const int node = gid >> 6;
  if (node >= NN) return;
  const int lane = threadIdx.x & 63;
  const int sub = lane >> 3;
  const int c8 = (lane & 7) * 8;
  const int e0 = rowptr[node], e1 = rowptr[node + 1];
  float a[8] = {0.f, 0.f, 0.f, 0.f, 0.f, 0.f, 0.f, 0.f};
  for (int e = e0 + sub; e < e1; e += 8) {
    uint4 v = *(const uint4*)&ebuf[(size_t)e * 64 + c8];
    a[0] += blo(v.x); a[1] += bhi(v.x);
    a[2] += blo(v.y); a[3] += bhi(v.y);
    a[4] += blo(v.z); a[5] += bhi(v.z);
    a[6] += blo(v.w); a[7] += bhi(v.w);
  }
#pragma unroll
  for (int k = 0; k < 8; ++k) {
    a[k] += __shfl_xor(a[k], 8);
    a[k] += __shfl_xor(a[k], 16);
    a[k] += __shfl_xor(a[k], 32);
  }
  if (sub == 0) {
    ushort4 p0, p1;
    p0.x = f2bf(a[0]); p0.y = f2bf(a[1]); p0.z = f2bf(a[2]); p0.w = f2bf(a[3]);
    p1.x = f2bf(a[4]); p1.y = f2bf(a[5]); p1.z = f2bf(a[6]); p1.w = f2bf(a[7]);
    *(ushort4*)&recvbf[(size_t)node * 64 + c8]     = p0;
    *(ushort4*)&recvbf[(size_t)node * 64 + c8 + 4] = p1;
  }
}

// ---- MFMA edge MLP. r11 = exact r5 revert (best known: edge 103us).
// 32 edges/block, 4 waves, acur single-buffer prefetch, raw barriers that do
// NOT drain vmcnt. QUARANTINED (all regressed vs this): operand-swap epilogue
// (r6/r7: +9us, b64 bank conflicts), M=64 w/ reg A-pipeline (r8: spill),
// M=64 on-demand A (r9: latency serialization), W1 LDS staging (r10: LDS
// pipe saturation, +43us). Weight loads stay global: L1-resident, cheap.
// K layout FIRST: [s 64][r 64][g 16|pad] = 160 (KC=5, AF=4)
//          else : [e 64][s 64][r 64][g 16|pad] = 224 (KC=7, AF=6)
template <int KC, bool FIRST>
__launch_bounds__(256, 2)
__global__ void edge_mfma(const u16* __restrict__ hbf, u16* __restrict__ ebuf,
                          const int* __restrict__ snd, const int* __restrict__ rcv,
                          const u16* __restrict__ gpad,
                          const u16* __restrict__ w1p, const float* __restrict__ b1,
                          const u16* __restrict__ w2p, const float* __restrict__ b2) {
  __shared__ __align__(16) u16 hid[32 * 136];
  __shared__ __align__(16) u16 easm[32 * 64];

  const int tid = threadIdx.x;
  const int lane = tid & 63;
  const int w = tid >> 6;
  const int l15 = lane & 15;
  const int q = lane >> 4;
  const int mr = w & 1;              // row-tile (16 rows) for both phases
  const int ntb1 = (w >> 1) * 4;     // phase-1 col-tiles (4 of 8)
  const int ntb2 = (w >> 1) * 2;     // phase-2 col-tiles (2 of 4)
  const int arow = mr * 16 + l15;
  const int NTILE = NE / 32;
  constexpr int AF = FIRST ? 4 : 6;  // per-tile A fragments (g is loop-invariant)

  float bb1[4], bb2[2];
#pragma unroll
  for (int i = 0; i < 4; ++i) bb1[i] = b1[(ntb1 + i) * 16 + l15];
#pragma unroll
  for (int i = 0; i < 2; ++i) bb2[i] = b2[(ntb2 + i) * 16 + l15];
  const bf16x8 gfrag = *(const bf16x8*)&gpad[q * 8];

  // ---- A pipeline: acur holds tile t's fragments; s_cur/r_cur hold t+1's idx
  bf16x8 acur[AF];
  int s_cur = 0, r_cur = 0;
  {
    const int t0 = blockIdx.x;
    if (t0 < NTILE) {
      const int eg0 = t0 * 32 + arow;
      const int s0 = snd[eg0], r0 = rcv[eg0];
      if (!FIRST) {
#pragma unroll
        for (int kc = 0; kc < 2; ++kc)
          acur[kc] = *(const bf16x8*)&ebuf[(size_t)eg0 * 64 + kc * 32 + q * 8];
      }
#pragma unroll
      for (int kc = 0; kc < 2; ++kc)
        acur[(FIRST ? 0 : 2) + kc] = *(const bf16x8*)&hbf[s0 * 64 + kc * 32 + q * 8];
#pragma unroll
      for (int kc = 0; kc < 2; ++kc)
        acur[(FIRST ? 2 : 4) + kc] = *(const bf16x8*)&hbf[r0 * 64 + kc * 32 + q * 8];
      const int t1 = t0 + gridDim.x;
      if (t1 < NTILE) {
        s_cur = snd[t1 * 32 + arow];
        r_cur = rcv[t1 * 32 + arow];
      }
    }
  }

  for (int tile = blockIdx.x; tile < NTILE; tile += gridDim.x) {
    const int ebase = tile * 32;

    // --- phase 1: hid = gelu(in @ W1 + b1)   [32 x 128] -- A from registers
    f32x4 acc[4];
#pragma unroll
    for (int i = 0; i < 4; ++i) acc[i] = (f32x4){bb1[i], bb1[i], bb1[i], bb1[i]};
#pragma unroll
    for (int kc = 0; kc < KC; ++kc) {
      bf16x8 a = (kc < AF) ? acur[kc] : gfrag;
#pragma unroll
      for (int i = 0; i < 4; ++i) {
        bf16x8 b = *(const bf16x8*)&w1p[(size_t)((kc * 8 + ntb1 + i) * 64 + lane) * 8];
        acc[i] = __builtin_amdgcn_mfma_f32_16x16x32_bf16(a, b, acc[i], 0, 0, 0);
      }
    }

    // --- prefetch next tile's A rows (reuses acur; lands during phase2+store)
    {
      const int tn = tile + gridDim.x;
      if (tn < NTILE) {
        const int egn = tn * 32 + arow;
        const int soffn = s_cur * 64;
        const int roffn = r_cur * 64;
        if (!FIRST) {
#pragma unroll
          for (int kc = 0; kc < 2; ++kc)
            acur[kc] = *(const bf16x8*)&ebuf[(size_t)egn * 64 + kc * 32 + q * 8];
        }
#pragma unroll
        for (int kc = 0; kc < 2; ++kc)
          acur[(FIRST ? 0 : 2) + kc] = *(const bf16x8*)&hbf[soffn + kc * 32 + q * 8];
#pragma unroll
        for (int kc = 0; kc < 2; ++kc)
          acur[(FIRST ? 2 : 4) + kc] = *(const bf16x8*)&hbf[roffn + kc * 32 + q * 8];
        const int tn2 = tn + gridDim.x;
        if (tn2 < NTILE) {
          s_cur = snd[tn2 * 32 + arow];
          r_cur = rcv[tn2 * 32 + arow];
        }
      }
    }

    // --- phase-1 epilogue: gelu -> hid (LDS)
#pragma unroll
    for (int i = 0; i < 4; ++i) {
      const int col = (ntb1 + i) * 16 + l15;
#pragma unroll
      for (int r4 = 0; r4 < 4; ++r4) {
        const int row = mr * 16 + q * 4 + r4;
        hid[row * 136 + col] = f2bf(gelu(acc[i][r4]));
      }
    }
    // barrier WITHOUT vmcnt drain (prefetch stays in flight)
    asm volatile("s_waitcnt lgkmcnt(0)" ::: "memory");
    __builtin_amdgcn_s_barrier();

    // --- phase 2: out = hid @ W2 + b2   [32 x 64] -> easm (bf16)
    {
      f32x4 acc2[2];
#pragma unroll
      for (int i = 0; i < 2; ++i) acc2[i] = (f32x4){bb2[i], bb2[i], bb2[i], bb2[i]};
#pragma unroll
      for (int kc = 0; kc < 4; ++kc) {
        bf16x8 a = *(const bf16x8*)&hid[arow * 136 + kc * 32 + q * 8];
#pragma unroll
        for (int i = 0; i < 2; ++i) {
          bf16x8 b = *(const bf16x8*)&w2p[(size_t)((kc * 4 + ntb2 + i) * 64 + lane) * 8];
          acc2[i] = __builtin_amdgcn_mfma_f32_16x16x32_bf16(a, b, acc2[i], 0, 0, 0);
        }
      }
#pragma unroll
      for (int i = 0; i < 2; ++i) {
        const int col = (ntb2 + i) * 16 + l15;
#pragma unroll
        for (int r4 = 0; r4 < 4; ++r4) {
          const int row = mr * 16 + q * 4 + r4;
          easm[row * 64 + col] = f2bf(acc2[i][r4]);
        }
      }
    }
    asm volatile("s_waitcnt lgkmcnt(0)" ::: "memory");
    __builtin_amdgcn_s_barrier();
    // --- coalesced e_out write: 256 threads x 16B = 32 rows x 128B
    ((uint4*)&ebuf[(size_t)ebase * 64])[tid] = ((const uint4*)easm)[tid];
  }
}

// ---- MFMA node MLP + skip + LayerNorm (r5 form). recv read as bf16 from
// agg_kernel output.
__launch_bounds__(256)
__global__ void node_mfma(float* __restrict__ h, u16* __restrict__ hbf,
                          const u16* __restrict__ recvbf,
                          const u16* __restrict__ gpad,
                          const u16* __restrict__ w1p, const float* __restrict__ b1,
                          const u16* __restrict__ w2p, const float* __restrict__ b2,
                          const float* __restrict__ lns, const float* __restrict__ lnb) {
  __shared__ __align__(16) u16 hid[32 * 136];
  __shared__ __align__(16) float outs[32 * 68];

  const int tid = threadIdx.x;
  const int lane = tid & 63;
  const int w = tid >> 6;
  const int l15 = lane & 15;
  const int q = lane >> 4;
  const int mr = w & 1;
  const int ntb1 = (w >> 1) * 4;
  const int ntb2 = (w >> 1) * 2;
  const int arow = mr * 16 + l15;

  float bb1[4], bb2[2];
#pragma unroll
  for (int i = 0; i < 4; ++i) bb1[i] = b1[(ntb1 + i) * 16 + l15];
#pragma unroll
  for (int i = 0; i < 2; ++i) bb2[i] = b2[(ntb2 + i) * 16 + l15];

  const int nrow = tid >> 3;
  const int jc = (tid & 7) * 8;
  float sc8[8], bi8[8];
#pragma unroll
  for (int k = 0; k < 8; ++k) { sc8[k] = lns[jc + k]; bi8[k] = lnb[jc + k]; }

  const int NT = (NN + 31) / 32;
  for (int tile = blockIdx.x; tile < NT; tile += gridDim.x) {
    const int nbase = tile * 32;
    const int na = min(nbase + arow, NN - 1) * 64;   // clamped A-row offset

    // --- phase 1
    {
      f32x4 acc[4];
#pragma unroll
      for (int i = 0; i < 4; ++i) acc[i] = (f32x4){bb1[i], bb1[i], bb1[i], bb1[i]};
#pragma unroll
      for (int kc = 0; kc < 5; ++kc) {
        bf16x8 a;
        if (kc < 2) {
          a = *(const bf16x8*)&hbf[na + kc * 32 + q * 8];
        } else if (kc < 4) {
          a = *(const bf16x8*)&recvbf[na + (kc - 2) * 32 + q * 8];
        } else {
          a = *(const bf16x8*)&gpad[q * 8];
        }
#pragma unroll
        for (int i = 0; i < 4; ++i) {
          bf16x8 b = *(const bf16x8*)&w1p[(size_t)((kc * 8 + ntb1 + i) * 64 + lane) * 8];
          acc[i] = __builtin_amdgcn_mfma_f32_16x16x32_bf16(a, b, acc[i], 0, 0, 0);
        }
      }
#pragma unroll
      for (int i = 0; i < 4; ++i) {
        const int col = (ntb1 + i) * 16 + l15;
#pragma unroll
        for (int r4 = 0; r4 < 4; ++r4) {
          const int row = mr * 16 + q * 4 + r4;
          hid[row * 136 + col] = f2bf(gelu(acc[i][r4]));
        }
      }
    }
    __syncthreads();
    // --- phase 2: upd = hid @ W2 + b2 -> outs (fp32 LDS)
    {
      f32x4 acc[2];
#pragma unroll
      for (int i = 0; i < 2; ++i) acc[i] = (f32x4){bb2[i], bb2[i], bb2[i], bb2[i]};
#pragma unroll
      for (int kc = 0; kc < 4; ++kc) {
        bf16x8 a = *(const bf16x8*)&hid[arow * 136 + kc * 32 + q * 8];
#pragma unroll
        for (int i = 0; i < 2; ++i) {
          bf16x8 b = *(const bf16x8*)&w2p[(size_t)((kc * 4 + ntb2 + i) * 64 + lane) * 8];
          acc[i] = __builtin_amdgcn_mfma_f32_16x16x32_bf16(a, b, acc[i], 0, 0, 0);
        }
      }
#pragma unroll
      for (int i = 0; i < 2; ++i) {
        const int col = (ntb2 + i) * 16 + l15;
#pragma unroll
        for (int r4 = 0; r4 < 4; ++r4) {
          const int row = mr * 16 + q * 4 + r4;
          outs[row * 68 + col] = acc[i][r4];
        }
      }
    }
    __syncthreads();
    // --- skip + LayerNorm: 8 threads per node row, 8 cols each
    {
      const int n = nbase + nrow;
      if (n < NN) {
        float x[8];
        float4 hv0 = *(const float4*)&h[n * 64 + jc];
        float4 hv1 = *(const float4*)&h[n * 64 + jc + 4];
        x[0] = hv0.x + outs[nrow * 68 + jc + 0];
        x[1] = hv0.y + outs[nrow * 68 + jc + 1];
        x[2] = hv0.z + outs[nrow * 68 + jc + 2];
        x[3] = hv0.w + outs[nrow * 68 + jc + 3];
        x[4] = hv1.x + outs[nrow * 68 + jc + 4];
        x[5] = hv1.y + outs[nrow * 68 + jc + 5];
        x[6] = hv1.z + outs[nrow * 68 + jc + 6];
        x[7] = hv1.w + outs[nrow * 68 + jc + 7];
        float s = 0.f, qq = 0.f;
#pragma unroll
        for (int k = 0; k < 8; ++k) { s += x[k]; qq += x[k] * x[k]; }
#pragma unroll
        for (int off = 1; off < 8; off <<= 1) {
          s += __shfl_xor(s, off);
          qq += __shfl_xor(qq, off);
        }
        float mean = s * (1.0f / 64.0f);
        float var = fmaxf(qq * (1.0f / 64.0f) - mean * mean, 0.0f);
        float rstd = rsqrtf(var + 1e-6f);
        float o[8];
        ushort4 ob0, ob1;
#pragma unroll
        for (int k = 0; k < 8; ++k) o[k] = (x[k] - mean) * rstd * sc8[k] + bi8[k];
        *(float4*)&h[n * 64 + jc]     = make_float4(o[0], o[1], o[2], o[3]);
        *(float4*)&h[n * 64 + jc + 4] = make_float4(o[4], o[5], o[6], o[7]);
        ob0.x = f2bf(o[0]); ob0.y = f2bf(o[1]); ob0.z = f2bf(o[2]); ob0.w = f2bf(o[3]);
        ob1.x = f2bf(o[4]); ob1.y = f2bf(o[5]); ob1.z = f2bf(o[6]); ob1.w = f2bf(o[7]);
        *(ushort4*)&hbf[n * 64 + jc]     = ob0;
        *(ushort4*)&hbf[n * 64 + jc + 4] = ob1;
      }
    }
    __syncthreads();   // protect hid/outs reuse next tile
  }
}

// Output dtype: float32 (reference returns fp32).
__global__ void decode_kernel(const float* __restrict__ h, const float* __restrict__ w,
                              const float* __restrict__ b, float* __restrict__ out) {
  int gid = blockIdx.x * blockDim.x + threadIdx.x;
  if (gid >= NN * INF) return;
  int n = gid / 7, f = gid % 7;
  float acc = b[f];
#pragma unroll
  for (int k = 0; k < LAT; ++k)
    acc = fmaf(h[n * 64 + k], w[k * 7 + f], acc);
  out[gid] = acc;
}

extern "C" void kernel_launch(void* const* d_in, const int* in_sizes, int n_in,
                              void* d_out, int out_size, void* d_ws, size_t ws_size,
                              hipStream_t stream) {
  const float* nodes = (const float*)d_in[0];
  const int* senders = (const int*)d_in[1];
  const int* recvrs  = (const int*)d_in[2];
  const float* g     = (const float*)d_in[3];
  const float* emb_w = (const float*)d_in[4];
  const float* emb_b = (const float*)d_in[5];
  const float* ew1f  = (const float*)d_in[6];
  const float* ew1r  = (const float*)d_in[7];
  const float* eb1   = (const float*)d_in[8];
  const float* ew2   = (const float*)d_in[9];
  const float* eb2   = (const float*)d_in[10];
  const float* nw1   = (const float*)d_in[11];
  const float* nb1   = (const float*)d_in[12];
  const float* nw2   = (const float*)d_in[13];
  const float* nb2   = (const float*)d_in[14];
  const float* lns   = (const float*)d_in[15];
  const float* lnb   = (const float*)d_in[16];
  const float* dw    = (const float*)d_in[17];
  const float* db    = (const float*)d_in[18];

  char* cur = (char*)d_ws;
  float* h      = (float*)cur;  cur += (size_t)NN * LAT * 4;        // 12.8 MB
  u16*   ebuf   = (u16*)cur;    cur += (size_t)NE * LAT * 2;        // 102.4 MB
  u16*   hbf    = (u16*)cur;    cur += (size_t)NN * LAT * 2;        // 6.4 MB
  u16*   recvbf = (u16*)cur;    cur += (size_t)NN * LAT * 2;        // 6.4 MB
  u16*   ew1p[3]; for (int t = 0; t < 3; ++t) { ew1p[t] = (u16*)cur; cur += 7 * 8 * 64 * 8 * 2; }
  u16*   ew2p[3]; for (int t = 0; t < 3; ++t) { ew2p[t] = (u16*)cur; cur += 4 * 4 * 64 * 8 * 2; }
  u16*   nw1p[3]; for (int t = 0; t < 3; ++t) { nw1p[t] = (u16*)cur; cur += 5 * 8 * 64 * 8 * 2; }
  u16*   nw2p[3]; for (int t = 0; t < 3; ++t) { nw2p[t] = (u16*)cur; cur += 4 * 4 * 64 * 8 * 2; }
  u16*   gpad   = (u16*)cur;    cur += 256;
  int*   cnt    = (int*)cur;    cur += ((size_t)NN * 4 + 255) & ~(size_t)255;
  int*   cursor = (int*)cur;    cur += ((size_t)NN * 4 + 255) & ~(size_t)255;
  int*   rowptr = (int*)cur;    cur += ((size_t)(NN + 1) * 4 + 255) & ~(size_t)255;
  int*   ssnd   = (int*)cur;    cur += (size_t)NE * 4;              // 3.2 MB
  int*   srcv   = (int*)cur;    cur += (size_t)NE * 4;              // 3.2 MB

  // one-time receiver counting sort (graph fixed across steps)
  hipMemsetAsync(cnt, 0, (size_t)NN * 4, stream);
  hist_kernel<<<(NE + 255) / 256, 256, 0, stream>>>(recvrs, cnt);
  scan_kernel<<<1, 1024, 0, stream>>>(cnt, rowptr, cursor);
  scatter_kernel<<<(NE + 255) / 256, 256, 0, stream>>>(senders, recvrs, cursor, ssnd, srcv);

  // single consolidated pre-pack dispatch (13 jobs)
  PackJobs J;
  J.src[0] = ew1f;                       J.dst[0] = ew1p[0]; J.K[0] = 144; J.N[0] = 128; J.KC[0] = 5;
  J.src[1] = ew1r;                       J.dst[1] = ew1p[1]; J.K[1] = 208; J.N[1] = 128; J.KC[1] = 7;
  J.src[2] = ew1r + (size_t)208 * 128;   J.dst[2] = ew1p[2]; J.K[2] = 208; J.N[2] = 128; J.KC[2] = 7;
  for (int t = 0; t < 3; ++t) {
    J.src[3 + t] = ew2 + (size_t)t * 128 * 64;  J.dst[3 + t] = ew2p[t]; J.K[3 + t] = 128; J.N[3 + t] = 64; J.KC[3 + t] = 4;
    J.src[6 + t] = nw1 + (size_t)t * 144 * 128; J.dst[6 + t] = nw1p[t]; J.K[6 + t] = 144; J.N[6 + t] = 128; J.KC[6 + t] = 5;
    J.src[9 + t] = nw2 + (size_t)t * 128 * 64;  J.dst[9 + t] = nw2p[t]; J.K[9 + t] = 128; J.N[9 + t] = 64; J.KC[9 + t] = 4;
  }
  J.src[12] = g; J.dst[12] = gpad; J.K[12] = 0; J.N[12] = 0; J.KC[12] = 0;
  pack_all<<<dim3(16, 13), 256, 0, stream>>>(J);

  embed_kernel<<<(NN * LAT + 255) / 256, 256, 0, stream>>>(nodes, emb_w, emb_b, h, hbf);

  for (int t = 0; t < 3; ++t) {
    if (t == 0)
      edge_mfma<5, true><<<2048, 256, 0, stream>>>(hbf, ebuf,
          ssnd, srcv, gpad, ew1p[0], eb1, ew2p[0], eb2);
    else
      edge_mfma<7, false><<<2048, 256, 0, stream>>>(hbf, ebuf,
          ssnd, srcv, gpad, ew1p[t], eb1 + t * 128, ew2p[t], eb2 + t * 64);
    agg_kernel<<<(NN * 64 + 255) / 256, 256, 0, stream>>>(ebuf, rowptr, recvbf);
    node_mfma<<<1563, 256, 0, stream>>>(h, hbf, recvbf, gpad,
        nw1p[t], nb1 + t * 128, nw2p[t], nb2 + t * 64,
        lns + t * 64, lnb + t * 64);
  }

  decode_kernel<<<(NN * INF + 255) / 256, 256, 0, stream>>>(h, dw, db, (float*)d_out);
}

// Round 12
// 629.177 us; speedup vs baseline: 1.2771x; 1.1230x over previous
//
#include <hip/hip_runtime.h>

#define NN 50000
#define NE 800000
#define INF 7
#define GD 16
#define LAT 64
#define HID 128

typedef unsigned short u16;
typedef __attribute__((ext_vector_type(8))) __bf16 bf16x8;
typedef __attribute__((ext_vector_type(4))) float f32x4;

__device__ __forceinline__ float bf2f(u16 u) {
  union { unsigned int i; float f; } v; v.i = ((unsigned int)u) << 16; return v.f;
}
__device__ __forceinline__ float blo(unsigned int u) {
  union { unsigned int i; float f; } v; v.i = u << 16; return v.f;
}
__device__ __forceinline__ float bhi(unsigned int u) {
  union { unsigned int i; float f; } v; v.i = u & 0xffff0000u; return v.f;
}
__device__ __forceinline__ u16 f2bf(float f) {
  union { float f; unsigned int i; } v; v.f = f;
  unsigned int x = v.i;
  return (u16)((x + 0x7fffu + ((x >> 16) & 1u)) >> 16);
}
// jax.nn.gelu approximate (tanh form) as x*sigmoid(2z) with v_rcp (r11-verified).
__device__ __forceinline__ float gelu(float x) {
  float u = x * x;
  float p = fmaf(0.044715f * u, x, x);
  float e = __expf(-1.5957691216057308f * p);
  return x * __builtin_amdgcn_rcpf(e + 1.0f);
}

// ---- consolidated weight pre-pack: 13 jobs in one dispatch.
struct PackJobs {
  const float* src[13];
  u16* dst[13];
  int K[13];
  int N[13];
  int KC[13];
};

__global__ void pack_all(PackJobs J) {
  const int j = blockIdx.y;
  const int KC = J.KC[j];
  const float* W = J.src[j];
  u16* out = J.dst[j];
  int t = blockIdx.x * blockDim.x + threadIdx.x;
  if (KC == 0) {            // gpad job
    if (t < 32) out[t] = (t < GD) ? f2bf(W[t]) : (u16)0;
    return;
  }
  const int K = J.K[j], N = J.N[j];
  const int NT = N >> 4;
  if (t >= KC * NT * 64) return;
  int l = t & 63;
  int nt = (t >> 6) % NT;
  int kc = t / (64 * NT);
  int n = nt * 16 + (l & 15);
  int kbase = kc * 32 + (l >> 4) * 8;
  ushort4 lo, hi;
  u16 v[8];
#pragma unroll
  for (int jj = 0; jj < 8; ++jj) {
    int k = kbase + jj;
    v[jj] = (k < K) ? f2bf(W[k * N + n]) : (u16)0;
  }
  lo.x = v[0]; lo.y = v[1]; lo.z = v[2]; lo.w = v[3];
  hi.x = v[4]; hi.y = v[5]; hi.z = v[6]; hi.w = v[7];
  ushort4* dst = (ushort4*)&out[(size_t)t * 8];
  dst[0] = lo; dst[1] = hi;
}

// ---- counting sort of edges by receiver (graph fixed across all 3 steps;
// sorted once, amortized). Removes ALL recv atomics from the hot loop.
__global__ void hist_kernel(const int* __restrict__ rcv, int* __restrict__ cnt) {
  int i = blockIdx.x * blockDim.x + threadIdx.x;
  if (i < NE) atomicAdd(&cnt[rcv[i]], 1);
}

// Chunked COALESCED block scan (r5: coalesced chunks fixed the 112us cost).
__launch_bounds__(1024)
__global__ void scan_kernel(const int* __restrict__ cnt, int* __restrict__ rowptr,
                            int* __restrict__ cursor) {
  __shared__ int wsum[16];
  const int t = threadIdx.x;
  const int lane = t & 63;
  const int wid = t >> 6;
  int carry = 0;
  for (int base = 0; base < NN; base += 1024) {
    const int i = base + t;
    int v = (i < NN) ? cnt[i] : 0;
    int x = v;
#pragma unroll
    for (int off = 1; off < 64; off <<= 1) {
      int y = __shfl_up(x, off);
      if (lane >= off) x += y;
    }
    if (lane == 63) wsum[wid] = x;
    __syncthreads();
    if (wid == 0 && lane < 16) {
      int s = wsum[lane];
#pragma unroll
      for (int off = 1; off < 16; off <<= 1) {
        int y = __shfl_up(s, off);
        if (lane >= off) s += y;
      }
      wsum[lane] = s;   // inclusive wave prefix
    }
    __syncthreads();
    const int excl = carry + (wid > 0 ? wsum[wid - 1] : 0) + (x - v);
    if (i < NN) { rowptr[i] = excl; cursor[i] = excl; }
    carry += wsum[15];  // chunk total (uniform across block)
    __syncthreads();    // protect wsum reuse next chunk
  }
  if (t == 0) rowptr[NN] = NE;
}

__global__ void scatter_kernel(const int* __restrict__ snd, const int* __restrict__ rcv,
                               int* __restrict__ cursor, int* __restrict__ ssnd,
                               int* __restrict__ srcv) {
  int i = blockIdx.x * blockDim.x + threadIdx.x;
  if (i >= NE) return;
  int r = rcv[i];
  int p = atomicAdd(&cursor[r], 1);
  ssnd[p] = snd[i];
  srcv[p] = r;
}

__global__ void embed_kernel(const float* __restrict__ nodes, const float* __restrict__ w,
                             const float* __restrict__ b, float* __restrict__ h,
                             u16* __restrict__ hbf) {
  int gid = blockIdx.x * blockDim.x + threadIdx.x;
  if (gid >= NN * LAT) return;
  int n = gid >> 6, j = gid & 63;
  float acc = b[j];
#pragma unroll
  for (int k = 0; k < INF; ++k)
    acc = fmaf(nodes[n * INF + k], w[k * LAT + j], acc);
  h[gid] = acc;
  hbf[gid] = f2bf(acc);
}

// ---- wave-per-node CSR segment-sum over receiver-sorted ebuf.
// 8 edges in flight (sub = lane>>3), 8 bf16 cols per lane via uint4 (16B).
__launch_bounds__(256)
__global__ void agg_kernel(const u16* __restrict__ ebuf, const int* __restrict__ rowptr,
                           u16* __restrict__ recvbf) {
  const int gid = blockIdx.x * blockDim.x + threadIdx.x;
  const int node = gid >> 6;
  if (node >= NN) return;
  const int lane = threadIdx.x & 63;
  const int sub = lane >> 3;
  const int c8 = (lane & 7) * 8;
  const int e0 = rowptr[node], e1 = rowptr[node + 1];
  float a[8] = {0.f, 0.f, 0.f, 0.f, 0.f, 0.f, 0.f, 0.f};
  for (int e = e0 + sub; e < e1; e += 8) {
    uint4 v = *(const uint4*)&ebuf[(size_t)e * 64 + c8];
    a[0] += blo(v.x); a[1] += bhi(v.x);
    a[2] += blo(v.y); a[3] += bhi(v.y);
    a[4] += blo(v.z); a[5] += bhi(v.z);
    a[6] += blo(v.w); a[7] += bhi(v.w);
  }
#pragma unroll
  for (int k = 0; k < 8; ++k) {
    a[k] += __shfl_xor(a[k], 8);
    a[k] += __shfl_xor(a[k], 16);
    a[k] += __shfl_xor(a[k], 32);
  }
  if (sub == 0) {
    ushort4 p0, p1;
    p0.x = f2bf(a[0]); p0.y = f2bf(a[1]); p0.z = f2bf(a[2]); p0.w = f2bf(a[3]);
    p1.x = f2bf(a[4]); p1.y = f2bf(a[5]); p1.z = f2bf(a[6]); p1.w = f2bf(a[7]);
    *(ushort4*)&recvbf[(size_t)node * 64 + c8]     = p0;
    *(ushort4*)&recvbf[(size_t)node * 64 + c8 + 4] = p1;
  }
}

// ---- MFMA edge MLP. r12 = byte-exact Round-5 kernel (best known: edge
// 103us, total 629.8us). CRITICAL: the b1f/b2f loop-invariant weight-frag
// arrays must stay -- r11 dropped them ("compiler can't hold them anyway")
// and regressed 103->132us: the declaration makes the compiler batch-issue
// weight loads per tile instead of interleaving dependent loads with MFMAs.
// QUARANTINED: operand-swap epilogue (r6/r7), M=64 blocking (r8/r9),
// W1 LDS staging (r10), de-hoisted weights (r11).
// K layout FIRST: [s 64][r 64][g 16|pad] = 160 (KC=5, AF=4)
//          else : [e 64][s 64][r 64][g 16|pad] = 224 (KC=7, AF=6)
template <int KC, bool FIRST>
__launch_bounds__(256, 2)
__global__ void edge_mfma(const u16* __restrict__ hbf, u16* __restrict__ ebuf,
                          const int* __restrict__ snd, const int* __restrict__ rcv,
                          const u16* __restrict__ gpad,
                          const u16* __restrict__ w1p, const float* __restrict__ b1,
                          const u16* __restrict__ w2p, const float* __restrict__ b2) {
  __shared__ __align__(16) u16 hid[32 * 136];
  __shared__ __align__(16) u16 easm[32 * 64];

  const int tid = threadIdx.x;
  const int lane = tid & 63;
  const int w = tid >> 6;
  const int l15 = lane & 15;
  const int q = lane >> 4;
  const int mr = w & 1;              // row-tile (16 rows) for both phases
  const int ntb1 = (w >> 1) * 4;     // phase-1 col-tiles (4 of 8)
  const int ntb2 = (w >> 1) * 2;     // phase-2 col-tiles (2 of 4)
  const int arow = mr * 16 + l15;
  const int NTILE = NE / 32;
  constexpr int AF = FIRST ? 4 : 6;  // per-tile A fragments (g is loop-invariant)

  float bb1[4], bb2[2];
#pragma unroll
  for (int i = 0; i < 4; ++i) bb1[i] = b1[(ntb1 + i) * 16 + l15];
#pragma unroll
  for (int i = 0; i < 2; ++i) bb2[i] = b2[(ntb2 + i) * 16 + l15];

  // ---- loop-invariant weight fragments -> registers (once per block)
  bf16x8 b1f[KC][4];
#pragma unroll
  for (int kc = 0; kc < KC; ++kc)
#pragma unroll
    for (int i = 0; i < 4; ++i)
      b1f[kc][i] = *(const bf16x8*)&w1p[(size_t)((kc * 8 + ntb1 + i) * 64 + lane) * 8];
  bf16x8 b2f[4][2];
#pragma unroll
  for (int kc = 0; kc < 4; ++kc)
#pragma unroll
    for (int i = 0; i < 2; ++i)
      b2f[kc][i] = *(const bf16x8*)&w2p[(size_t)((kc * 4 + ntb2 + i) * 64 + lane) * 8];
  const bf16x8 gfrag = *(const bf16x8*)&gpad[q * 8];

  // ---- A pipeline: acur holds tile t's fragments; s_cur/r_cur hold t+1's idx
  bf16x8 acur[AF];
  int s_cur = 0, r_cur = 0;
  {
    const int t0 = blockIdx.x;
    if (t0 < NTILE) {
      const int eg0 = t0 * 32 + arow;
      const int s0 = snd[eg0], r0 = rcv[eg0];
      if (!FIRST) {
#pragma unroll
        for (int kc = 0; kc < 2; ++kc)
          acur[kc] = *(const bf16x8*)&ebuf[(size_t)eg0 * 64 + kc * 32 + q * 8];
      }
#pragma unroll
      for (int kc = 0; kc < 2; ++kc)
        acur[(FIRST ? 0 : 2) + kc] = *(const bf16x8*)&hbf[s0 * 64 + kc * 32 + q * 8];
#pragma unroll
      for (int kc = 0; kc < 2; ++kc)
        acur[(FIRST ? 2 : 4) + kc] = *(const bf16x8*)&hbf[r0 * 64 + kc * 32 + q * 8];
      const int t1 = t0 + gridDim.x;
      if (t1 < NTILE) {
        s_cur = snd[t1 * 32 + arow];
        r_cur = rcv[t1 * 32 + arow];
      }
    }
  }

  for (int tile = blockIdx.x; tile < NTILE; tile += gridDim.x) {
    const int ebase = tile * 32;

    // --- phase 1: hid = gelu(in @ W1 + b1)   [32 x 128] -- all-register MFMA
    f32x4 acc[4];
#pragma unroll
    for (int i = 0; i < 4; ++i) acc[i] = (f32x4){bb1[i], bb1[i], bb1[i], bb1[i]};
#pragma unroll
    for (int kc = 0; kc < KC; ++kc) {
      bf16x8 a = (kc < AF) ? acur[kc] : gfrag;
#pragma unroll
      for (int i = 0; i < 4; ++i)
        acc[i] = __builtin_amdgcn_mfma_f32_16x16x32_bf16(a, b1f[kc][i], acc[i], 0, 0, 0);
    }

    // --- prefetch next tile's A rows (reuses acur; lands during phase2+store)
    {
      const int tn = tile + gridDim.x;
      if (tn < NTILE) {
        const int egn = tn * 32 + arow;
        const int soffn = s_cur * 64;
        const int roffn = r_cur * 64;
        if (!FIRST) {
#pragma unroll
          for (int kc = 0; kc < 2; ++kc)
            acur[kc] = *(const bf16x8*)&ebuf[(size_t)egn * 64 + kc * 32 + q * 8];
        }
#pragma unroll
        for (int kc = 0; kc < 2; ++kc)
          acur[(FIRST ? 0 : 2) + kc] = *(const bf16x8*)&hbf[soffn + kc * 32 + q * 8];
#pragma unroll
        for (int kc = 0; kc < 2; ++kc)
          acur[(FIRST ? 2 : 4) + kc] = *(const bf16x8*)&hbf[roffn + kc * 32 + q * 8];
        const int tn2 = tn + gridDim.x;
        if (tn2 < NTILE) {
          s_cur = snd[tn2 * 32 + arow];
          r_cur = rcv[tn2 * 32 + arow];
        }
      }
    }

    // --- phase-1 epilogue: gelu -> hid (LDS)
#pragma unroll
    for (int i = 0; i < 4; ++i) {
      const int col = (ntb1 + i) * 16 + l15;
#pragma unroll
      for (int r4 = 0; r4 < 4; ++r4) {
        const int row = mr * 16 + q * 4 + r4;
        hid[row * 136 + col] = f2bf(gelu(acc[i][r4]));
      }
    }
    // barrier WITHOUT vmcnt drain (prefetch stays in flight)
    asm volatile("s_waitcnt lgkmcnt(0)" ::: "memory");
    __builtin_amdgcn_s_barrier();

    // --- phase 2: out = hid @ W2 + b2   [32 x 64] -> easm (bf16)
    {
      f32x4 acc2[2];
#pragma unroll
      for (int i = 0; i < 2; ++i) acc2[i] = (f32x4){bb2[i], bb2[i], bb2[i], bb2[i]};
#pragma unroll
      for (int kc = 0; kc < 4; ++kc) {
        bf16x8 a = *(const bf16x8*)&hid[arow * 136 + kc * 32 + q * 8];
#pragma unroll
        for (int i = 0; i < 2; ++i)
          acc2[i] = __builtin_amdgcn_mfma_f32_16x16x32_bf16(a, b2f[kc][i], acc2[i], 0, 0, 0);
      }
#pragma unroll
      for (int i = 0; i < 2; ++i) {
        const int col = (ntb2 + i) * 16 + l15;
#pragma unroll
        for (int r4 = 0; r4 < 4; ++r4) {
          const int row = mr * 16 + q * 4 + r4;
          easm[row * 64 + col] = f2bf(acc2[i][r4]);
        }
      }
    }
    asm volatile("s_waitcnt lgkmcnt(0)" ::: "memory");
    __builtin_amdgcn_s_barrier();
    // --- coalesced e_out write: 256 threads x 16B = 32 rows x 128B
    ((uint4*)&ebuf[(size_t)ebase * 64])[tid] = ((const uint4*)easm)[tid];
  }
}

// ---- MFMA node MLP + skip + LayerNorm (r5 form). recv read as bf16 from
// agg_kernel output.
__launch_bounds__(256)
__global__ void node_mfma(float* __restrict__ h, u16* __restrict__ hbf,
                          const u16* __restrict__ recvbf,
                          const u16* __restrict__ gpad,
                          const u16* __restrict__ w1p, const float* __restrict__ b1,
                          const u16* __restrict__ w2p, const float* __restrict__ b2,
                          const float* __restrict__ lns, const float* __restrict__ lnb) {
  __shared__ __align__(16) u16 hid[32 * 136];
  __shared__ __align__(16) float outs[32 * 68];

  const int tid = threadIdx.x;
  const int lane = tid & 63;
  const int w = tid >> 6;
  const int l15 = lane & 15;
  const int q = lane >> 4;
  const int mr = w & 1;
  const int ntb1 = (w >> 1) * 4;
  const int ntb2 = (w >> 1) * 2;
  const int arow = mr * 16 + l15;

  float bb1[4], bb2[2];
#pragma unroll
  for (int i = 0; i < 4; ++i) bb1[i] = b1[(ntb1 + i) * 16 + l15];
#pragma unroll
  for (int i = 0; i < 2; ++i) bb2[i] = b2[(ntb2 + i) * 16 + l15];

  const int nrow = tid >> 3;
  const int jc = (tid & 7) * 8;
  float sc8[8], bi8[8];
#pragma unroll
  for (int k = 0; k < 8; ++k) { sc8[k] = lns[jc + k]; bi8[k] = lnb[jc + k]; }

  const int NT = (NN + 31) / 32;
  for (int tile = blockIdx.x; tile < NT; tile += gridDim.x) {
    const int nbase = tile * 32;
    const int na = min(nbase + arow, NN - 1) * 64;   // clamped A-row offset

    // --- phase 1
    {
      f32x4 acc[4];
#pragma unroll
      for (int i = 0; i < 4; ++i) acc[i] = (f32x4){bb1[i], bb1[i], bb1[i], bb1[i]};
#pragma unroll
      for (int kc = 0; kc < 5; ++kc) {
        bf16x8 a;
        if (kc < 2) {
          a = *(const bf16x8*)&hbf[na + kc * 32 + q * 8];
        } else if (kc < 4) {
          a = *(const bf16x8*)&recvbf[na + (kc - 2) * 32 + q * 8];
        } else {
          a = *(const bf16x8*)&gpad[q * 8];
        }
#pragma unroll
        for (int i = 0; i < 4; ++i) {
          bf16x8 b = *(const bf16x8*)&w1p[(size_t)((kc * 8 + ntb1 + i) * 64 + lane) * 8];
          acc[i] = __builtin_amdgcn_mfma_f32_16x16x32_bf16(a, b, acc[i], 0, 0, 0);
        }
      }
#pragma unroll
      for (int i = 0; i < 4; ++i) {
        const int col = (ntb1 + i) * 16 + l15;
#pragma unroll
        for (int r4 = 0; r4 < 4; ++r4) {
          const int row = mr * 16 + q * 4 + r4;
          hid[row * 136 + col] = f2bf(gelu(acc[i][r4]));
        }
      }
    }
    __syncthreads();
    // --- phase 2: upd = hid @ W2 + b2 -> outs (fp32 LDS)
    {
      f32x4 acc[2];
#pragma unroll
      for (int i = 0; i < 2; ++i) acc[i] = (f32x4){bb2[i], bb2[i], bb2[i], bb2[i]};
#pragma unroll
      for (int kc = 0; kc < 4; ++kc) {
        bf16x8 a = *(const bf16x8*)&hid[arow * 136 + kc * 32 + q * 8];
#pragma unroll
        for (int i = 0; i < 2; ++i) {
          bf16x8 b = *(const bf16x8*)&w2p[(size_t)((kc * 4 + ntb2 + i) * 64 + lane) * 8];
          acc[i] = __builtin_amdgcn_mfma_f32_16x16x32_bf16(a, b, acc[i], 0, 0, 0);
        }
      }
#pragma unroll
      for (int i = 0; i < 2; ++i) {
        const int col = (ntb2 + i) * 16 + l15;
#pragma unroll
        for (int r4 = 0; r4 < 4; ++r4) {
          const int row = mr * 16 + q * 4 + r4;
          outs[row * 68 + col] = acc[i][r4];
        }
      }
    }
    __syncthreads();
    // --- skip + LayerNorm: 8 threads per node row, 8 cols each
    {
      const int n = nbase + nrow;
      if (n < NN) {
        float x[8];
        float4 hv0 = *(const float4*)&h[n * 64 + jc];
        float4 hv1 = *(const float4*)&h[n * 64 + jc + 4];
        x[0] = hv0.x + outs[nrow * 68 + jc + 0];
        x[1] = hv0.y + outs[nrow * 68 + jc + 1];
        x[2] = hv0.z + outs[nrow * 68 + jc + 2];
        x[3] = hv0.w + outs[nrow * 68 + jc + 3];
        x[4] = hv1.x + outs[nrow * 68 + jc + 4];
        x[5] = hv1.y + outs[nrow * 68 + jc + 5];
        x[6] = hv1.z + outs[nrow * 68 + jc + 6];
        x[7] = hv1.w + outs[nrow * 68 + jc + 7];
        float s = 0.f, qq = 0.f;
#pragma unroll
        for (int k = 0; k < 8; ++k) { s += x[k]; qq += x[k] * x[k]; }
#pragma unroll
        for (int off = 1; off < 8; off <<= 1) {
          s += __shfl_xor(s, off);
          qq += __shfl_xor(qq, off);
        }
        float mean = s * (1.0f / 64.0f);
        float var = fmaxf(qq * (1.0f / 64.0f) - mean * mean, 0.0f);
        float rstd = rsqrtf(var + 1e-6f);
        float o[8];
        ushort4 ob0, ob1;
#pragma unroll
        for (int k = 0; k < 8; ++k) o[k] = (x[k] - mean) * rstd * sc8[k] + bi8[k];
        *(float4*)&h[n * 64 + jc]     = make_float4(o[0], o[1], o[2], o[3]);
        *(float4*)&h[n * 64 + jc + 4] = make_float4(o[4], o[5], o[6], o[7]);
        ob0.x = f2bf(o[0]); ob0.y = f2bf(o[1]); ob0.z = f2bf(o[2]); ob0.w = f2bf(o[3]);
        ob1.x = f2bf(o[4]); ob1.y = f2bf(o[5]); ob1.z = f2bf(o[6]); ob1.w = f2bf(o[7]);
        *(ushort4*)&hbf[n * 64 + jc]     = ob0;
        *(ushort4*)&hbf[n * 64 + jc + 4] = ob1;
      }
    }
    __syncthreads();   // protect hid/outs reuse next tile
  }
}

// Output dtype: float32 (reference returns fp32).
__global__ void decode_kernel(const float* __restrict__ h, const float* __restrict__ w,
                              const float* __restrict__ b, float* __restrict__ out) {
  int gid = blockIdx.x * blockDim.x + threadIdx.x;
  if (gid >= NN * INF) return;
  int n = gid / 7, f = gid % 7;
  float acc = b[f];
#pragma unroll
  for (int k = 0; k < LAT; ++k)
    acc = fmaf(h[n * 64 + k], w[k * 7 + f], acc);
  out[gid] = acc;
}

extern "C" void kernel_launch(void* const* d_in, const int* in_sizes, int n_in,
                              void* d_out, int out_size, void* d_ws, size_t ws_size,
                              hipStream_t stream) {
  const float* nodes = (const float*)d_in[0];
  const int* senders = (const int*)d_in[1];
  const int* recvrs  = (const int*)d_in[2];
  const float* g     = (const float*)d_in[3];
  const float* emb_w = (const float*)d_in[4];
  const float* emb_b = (const float*)d_in[5];
  const float* ew1f  = (const float*)d_in[6];
  const float* ew1r  = (const float*)d_in[7];
  const float* eb1   = (const float*)d_in[8];
  const float* ew2   = (const float*)d_in[9];
  const float* eb2   = (const float*)d_in[10];
  const float* nw1   = (const float*)d_in[11];
  const float* nb1   = (const float*)d_in[12];
  const float* nw2   = (const float*)d_in[13];
  const float* nb2   = (const float*)d_in[14];
  const float* lns   = (const float*)d_in[15];
  const float* lnb   = (const float*)d_in[16];
  const float* dw    = (const float*)d_in[17];
  const float* db    = (const float*)d_in[18];

  char* cur = (char*)d_ws;
  float* h      = (float*)cur;  cur += (size_t)NN * LAT * 4;        // 12.8 MB
  u16*   ebuf   = (u16*)cur;    cur += (size_t)NE * LAT * 2;        // 102.4 MB
  u16*   hbf    = (u16*)cur;    cur += (size_t)NN * LAT * 2;        // 6.4 MB
  u16*   recvbf = (u16*)cur;    cur += (size_t)NN * LAT * 2;        // 6.4 MB
  u16*   ew1p[3]; for (int t = 0; t < 3; ++t) { ew1p[t] = (u16*)cur; cur += 7 * 8 * 64 * 8 * 2; }
  u16*   ew2p[3]; for (int t = 0; t < 3; ++t) { ew2p[t] = (u16*)cur; cur += 4 * 4 * 64 * 8 * 2; }
  u16*   nw1p[3]; for (int t = 0; t < 3; ++t) { nw1p[t] = (u16*)cur; cur += 5 * 8 * 64 * 8 * 2; }
  u16*   nw2p[3]; for (int t = 0; t < 3; ++t) { nw2p[t] = (u16*)cur; cur += 4 * 4 * 64 * 8 * 2; }
  u16*   gpad   = (u16*)cur;    cur += 256;
  int*   cnt    = (int*)cur;    cur += ((size_t)NN * 4 + 255) & ~(size_t)255;
  int*   cursor = (int*)cur;    cur += ((size_t)NN * 4 + 255) & ~(size_t)255;
  int*   rowptr = (int*)cur;    cur += ((size_t)(NN + 1) * 4 + 255) & ~(size_t)255;
  int*   ssnd   = (int*)cur;    cur += (size_t)NE * 4;              // 3.2 MB
  int*   srcv   = (int*)cur;    cur += (size_t)NE * 4;              // 3.2 MB

  // one-time receiver counting sort (graph fixed across steps)
  hipMemsetAsync(cnt, 0, (size_t)NN * 4, stream);
  hist_kernel<<<(NE + 255) / 256, 256, 0, stream>>>(recvrs, cnt);
  scan_kernel<<<1, 1024, 0, stream>>>(cnt, rowptr, cursor);
  scatter_kernel<<<(NE + 255) / 256, 256, 0, stream>>>(senders, recvrs, cursor, ssnd, srcv);

  // single consolidated pre-pack dispatch (13 jobs)
  PackJobs J;
  J.src[0] = ew1f;                       J.dst[0] = ew1p[0]; J.K[0] = 144; J.N[0] = 128; J.KC[0] = 5;
  J.src[1] = ew1r;                       J.dst[1] = ew1p[1]; J.K[1] = 208; J.N[1] = 128; J.KC[1] = 7;
  J.src[2] = ew1r + (size_t)208 * 128;   J.dst[2] = ew1p[2]; J.K[2] = 208; J.N[2] = 128; J.KC[2] = 7;
  for (int t = 0; t < 3; ++t) {
    J.src[3 + t] = ew2 + (size_t)t * 128 * 64;  J.dst[3 + t] = ew2p[t]; J.K[3 + t] = 128; J.N[3 + t] = 64; J.KC[3 + t] = 4;
    J.src[6 + t] = nw1 + (size_t)t * 144 * 128; J.dst[6 + t] = nw1p[t]; J.K[6 + t] = 144; J.N[6 + t] = 128; J.KC[6 + t] = 5;
    J.src[9 + t] = nw2 + (size_t)t * 128 * 64;  J.dst[9 + t] = nw2p[t]; J.K[9 + t] = 128; J.N[9 + t] = 64; J.KC[9 + t] = 4;
  }
  J.src[12] = g; J.dst[12] = gpad; J.K[12] = 0; J.N[12] = 0; J.KC[12] = 0;
  pack_all<<<dim3(16, 13), 256, 0, stream>>>(J);

  embed_kernel<<<(NN * LAT + 255) / 256, 256, 0, stream>>>(nodes, emb_w, emb_b, h, hbf);

  for (int t = 0; t < 3; ++t) {
    if (t == 0)
      edge_mfma<5, true><<<2048, 256, 0, stream>>>(hbf, ebuf,
          ssnd, srcv, gpad, ew1p[0], eb1, ew2p[0], eb2);
    else
      edge_mfma<7, false><<<2048, 256, 0, stream>>>(hbf, ebuf,
          ssnd, srcv, gpad, ew1p[t], eb1 + t * 128, ew2p[t], eb2 + t * 64);
    agg_kernel<<<(NN * 64 + 255) / 256, 256, 0, stream>>>(ebuf, rowptr, recvbf);
    node_mfma<<<1563, 256, 0, stream>>>(h, hbf, recvbf, gpad,
        nw1p[t], nb1 + t * 128, nw2p[t], nb2 + t * 64,
        lns + t * 64, lnb + t * 64);
  }

  decode_kernel<<<(NN * INF + 255) / 256, 256, 0, stream>>>(h, dw, db, (float*)d_out);
}